// Round 1
// baseline (1289.520 us; speedup 1.0000x reference)
//
#include <hip/hip_runtime.h>
#include <hip/hip_bf16.h>
#include <cstdint>
#include <cstddef>

#define HIDN 2048
#define NHEAD 16
#define HDIM 128
#define INTERN 5632
#define SEQ 4096

typedef __bf16 bf16x8 __attribute__((ext_vector_type(8)));
typedef float f32x4 __attribute__((ext_vector_type(4)));
typedef unsigned short u16x8 __attribute__((ext_vector_type(8)));

__device__ __forceinline__ float bf2f(unsigned short u) {
  unsigned v = ((unsigned)u) << 16; float f; __builtin_memcpy(&f, &v, 4); return f;
}
__device__ __forceinline__ unsigned short f2bf(float f) {
  unsigned u; __builtin_memcpy(&u, &f, 4);
  unsigned r = 0x7FFFu + ((u >> 16) & 1u);
  return (unsigned short)((u + r) >> 16);
}
// async global->LDS, 16B per lane. dst must be wave-linear: base + lane*16B.
__device__ __forceinline__ void gl_lds16(const unsigned short* g, unsigned short* l) {
  __builtin_amdgcn_global_load_lds((unsigned int __attribute__((address_space(1)))*)g,
                                   (unsigned int __attribute__((address_space(3)))*)l,
                                   16, 0, 0);
}

// ---------------- RMSNorm: fp32 row -> bf16 row ----------------
__global__ __launch_bounds__(256) void rmsnorm_kernel(const float* __restrict__ x,
                                                      const float* __restrict__ wgt,
                                                      unsigned short* __restrict__ out) {
  const int tid = threadIdx.x;
  const size_t base = (size_t)blockIdx.x * HIDN + tid * 8;
  f32x4 a = *(const f32x4*)(x + base);
  f32x4 b = *(const f32x4*)(x + base + 4);
  float ss = a[0]*a[0]+a[1]*a[1]+a[2]*a[2]+a[3]*a[3]
           + b[0]*b[0]+b[1]*b[1]+b[2]*b[2]+b[3]*b[3];
#pragma unroll
  for (int off = 32; off >= 1; off >>= 1) ss += __shfl_xor(ss, off, 64);
  __shared__ float red[4];
  if ((tid & 63) == 0) red[tid >> 6] = ss;
  __syncthreads();
  float tot = red[0] + red[1] + red[2] + red[3];
  float sc = 1.f / sqrtf(tot * (1.f / HIDN) + 1e-6f);
  f32x4 w0 = *(const f32x4*)(wgt + tid * 8);
  f32x4 w1 = *(const f32x4*)(wgt + tid * 8 + 4);
  u16x8 o;
#pragma unroll
  for (int i = 0; i < 4; ++i) { o[i] = f2bf(a[i] * sc * w0[i]); o[i+4] = f2bf(b[i] * sc * w1[i]); }
  *(u16x8*)(out + base) = o;
}

// ---------------- transpose fp32 [R][C] -> bf16 [C][R] ----------------
__global__ __launch_bounds__(256) void transpose_f2b(const float* __restrict__ in,
                                                     unsigned short* __restrict__ out,
                                                     int R, int C) {
  __shared__ float tile[32][33];
  const int bx = blockIdx.x * 32, by = blockIdx.y * 32;
  const int tx = threadIdx.x & 31, ty = threadIdx.x >> 5;
#pragma unroll
  for (int i = 0; i < 32; i += 8)
    tile[ty + i][tx] = in[(size_t)(by + ty + i) * C + bx + tx];
  __syncthreads();
#pragma unroll
  for (int i = 0; i < 32; i += 8)
    out[(size_t)(bx + ty + i) * R + by + tx] = f2bf(tile[tx][ty + i]);
}

// ---------------- transpose bf16 [R][C] -> bf16 [C][R] ----------------
__global__ __launch_bounds__(256) void transpose_b2b(const unsigned short* __restrict__ in,
                                                     unsigned short* __restrict__ out,
                                                     int R, int C) {
  __shared__ unsigned short tile[32][33];
  const int bx = blockIdx.x * 32, by = blockIdx.y * 32;
  const int tx = threadIdx.x & 31, ty = threadIdx.x >> 5;
#pragma unroll
  for (int i = 0; i < 32; i += 8)
    tile[ty + i][tx] = in[(size_t)(by + ty + i) * C + bx + tx];
  __syncthreads();
#pragma unroll
  for (int i = 0; i < 32; i += 8)
    out[(size_t)(bx + ty + i) * R + by + tx] = tile[tx][ty + i];
}

// ---------------- RoPE in-place on bf16 [SEQ][HIDN] ----------------
__global__ __launch_bounds__(256) void rope_kernel(unsigned short* __restrict__ v,
                                                   const float* __restrict__ cosb,
                                                   const float* __restrict__ sinb) {
  const int s = blockIdx.x, tid = threadIdx.x;
  const size_t base = (size_t)s * HIDN + tid * 8;
  u16x8 u = *(const u16x8*)(v + base);
  const int j0 = ((tid * 8) & 127) >> 1;
  const float* cr = cosb + s * 64 + j0;
  const float* sr = sinb + s * 64 + j0;
  u16x8 o;
#pragma unroll
  for (int p = 0; p < 4; ++p) {
    float re = bf2f(u[2*p]), im = bf2f(u[2*p+1]);
    float c = cr[p], sn = sr[p];
    o[2*p]   = f2bf(re * c - im * sn);
    o[2*p+1] = f2bf(re * sn + im * c);
  }
  *(u16x8*)(v + base) = o;
}

// ---------------- bf16 GEMM, m97 structure: C[M,N] = A[M,K] * Bt[N,K]^T ----------------
// EPI 0: outB = bf16(acc)
// EPI 1: outF = res + acc          (fp32 residual store)
// EPI 2: outB = bf16(silu(gate)*acc)
template<int EPI>
__global__ __launch_bounds__(256) void gemm_bt(const unsigned short* __restrict__ A,
                                               const unsigned short* __restrict__ Bt,
                                               int M, int N, int K,
                                               float* __restrict__ outF,
                                               unsigned short* __restrict__ outB,
                                               const float* __restrict__ res,
                                               const unsigned short* __restrict__ gate) {
  __shared__ unsigned short As[128 * 32];
  __shared__ unsigned short Bs[128 * 32];
  const int tid = threadIdx.x;
  const int w = tid >> 6, l = tid & 63;
  const int lr = l & 15, lk = (l >> 4) * 8;
  const int m0 = blockIdx.y * 128, n0 = blockIdx.x * 128;
  const int wm = (w >> 1) * 64, wn = (w & 1) * 64;

  f32x4 acc[4][4];
#pragma unroll
  for (int i = 0; i < 4; ++i)
#pragma unroll
    for (int j = 0; j < 4; ++j) acc[i][j] = (f32x4){0.f, 0.f, 0.f, 0.f};

  const int srow = tid >> 2, scol = (tid & 3) * 8;
  const unsigned short* a0 = A + (size_t)(m0 + srow) * K + scol;
  const unsigned short* a1 = A + (size_t)(m0 + 64 + srow) * K + scol;
  const unsigned short* b0 = Bt + (size_t)(n0 + srow) * K + scol;
  const unsigned short* b1 = Bt + (size_t)(n0 + 64 + srow) * K + scol;
  unsigned short* ad0 = As + tid * 8;
  unsigned short* ad1 = As + 2048 + tid * 8;
  unsigned short* bd0 = Bs + tid * 8;
  unsigned short* bd1 = Bs + 2048 + tid * 8;

  for (int k0 = 0; k0 < K; k0 += 32) {
    gl_lds16(a0 + k0, ad0);
    gl_lds16(a1 + k0, ad1);
    gl_lds16(b0 + k0, bd0);
    gl_lds16(b1 + k0, bd1);
    __syncthreads();
    bf16x8 af[4], bfr[4];
#pragma unroll
    for (int m = 0; m < 4; ++m) af[m] = *(const bf16x8*)&As[(wm + m * 16 + lr) * 32 + lk];
#pragma unroll
    for (int n = 0; n < 4; ++n) bfr[n] = *(const bf16x8*)&Bs[(wn + n * 16 + lr) * 32 + lk];
#pragma unroll
    for (int m = 0; m < 4; ++m)
#pragma unroll
      for (int n = 0; n < 4; ++n)
        acc[m][n] = __builtin_amdgcn_mfma_f32_16x16x32_bf16(af[m], bfr[n], acc[m][n], 0, 0, 0);
    __syncthreads();
  }

#pragma unroll
  for (int m = 0; m < 4; ++m)
#pragma unroll
    for (int n = 0; n < 4; ++n)
#pragma unroll
      for (int r = 0; r < 4; ++r) {
        const int row = m0 + wm + m * 16 + (l >> 4) * 4 + r;
        const int col = n0 + wn + n * 16 + lr;
        const size_t idx = (size_t)row * N + col;
        float v = acc[m][n][r];
        if (EPI == 0) {
          outB[idx] = f2bf(v);
        } else if (EPI == 1) {
          outF[idx] = res[idx] + v;
        } else {
          float g = bf2f(gate[idx]);
          float s = g / (1.f + __expf(-g));
          outB[idx] = f2bf(s * v);
        }
      }
}

// ---------------- causal flash attention ----------------
// Q,K: bf16 [SEQ][HIDN] (rope'd). Vt: bf16 [HIDN][SEQ]. Ob: bf16 [SEQ][HIDN].
// Block: (q-tile of 64, head). 4 waves x 16 q-rows. KV-tiles of 32.
__global__ __launch_bounds__(256) void attn_kernel(const unsigned short* __restrict__ Q,
                                                   const unsigned short* __restrict__ Kb,
                                                   const unsigned short* __restrict__ Vt,
                                                   unsigned short* __restrict__ Ob) {
  __shared__ unsigned short Ks[32 * 128];
  __shared__ unsigned short Vs[128 * 32];
  __shared__ unsigned short Ps[4 * 512];
  const int tid = threadIdx.x, w = tid >> 6, l = tid & 63;
  const int lr = l & 15, lk = (l >> 4) * 8, lg = (l >> 4) * 4;
  const int h = blockIdx.y;
  const int qb0 = blockIdx.x * 64;
  const int qrow = qb0 + w * 16;

  bf16x8 qf[4];
#pragma unroll
  for (int d = 0; d < 4; ++d)
    qf[d] = *(const bf16x8*)(Q + (size_t)(qrow + lr) * HIDN + h * HDIM + d * 32 + lk);

  float mrow[4] = {-1e30f, -1e30f, -1e30f, -1e30f};
  float lsum[4] = {0.f, 0.f, 0.f, 0.f};
  f32x4 oacc[8];
#pragma unroll
  for (int d = 0; d < 8; ++d) oacc[d] = (f32x4){0.f, 0.f, 0.f, 0.f};

  const int krow = tid >> 4, kcol = (tid & 15) * 8;
  const int vrow = tid >> 2, vcol = (tid & 3) * 8;
  const int nt = qb0 / 32 + 2;

  for (int t = 0; t < nt; ++t) {
    const int kv0 = t * 32;
    gl_lds16(Kb + (size_t)(kv0 + krow) * HIDN + h * HDIM + kcol, Ks + tid * 8);
    gl_lds16(Kb + (size_t)(kv0 + 16 + krow) * HIDN + h * HDIM + kcol, Ks + 2048 + tid * 8);
    gl_lds16(Vt + (size_t)(h * HDIM + vrow) * SEQ + kv0 + vcol, Vs + tid * 8);
    gl_lds16(Vt + (size_t)(h * HDIM + 64 + vrow) * SEQ + kv0 + vcol, Vs + 2048 + tid * 8);
    __syncthreads();
    if (kv0 <= qrow + 15) {  // wave-uniform: skip fully-masked tiles
      f32x4 sa[2];
      sa[0] = (f32x4){0.f, 0.f, 0.f, 0.f};
      sa[1] = (f32x4){0.f, 0.f, 0.f, 0.f};
#pragma unroll
      for (int cf = 0; cf < 2; ++cf)
#pragma unroll
        for (int d = 0; d < 4; ++d) {
          bf16x8 kf = *(const bf16x8*)&Ks[(cf * 16 + lr) * 128 + d * 32 + lk];
          sa[cf] = __builtin_amdgcn_mfma_f32_16x16x32_bf16(qf[d], kf, sa[cf], 0, 0, 0);
        }
      // scale + causal mask
#pragma unroll
      for (int cf = 0; cf < 2; ++cf)
#pragma unroll
        for (int r = 0; r < 4; ++r) {
          float v = sa[cf][r] * 0.08838834764831845f;
          const int qi = qrow + lg + r;
          const int ki = kv0 + cf * 16 + lr;
          sa[cf][r] = (ki > qi) ? -1e30f : v;
        }
      float al[4];
#pragma unroll
      for (int r = 0; r < 4; ++r) {
        float v = fmaxf(sa[0][r], sa[1][r]);
#pragma unroll
        for (int off = 8; off >= 1; off >>= 1) v = fmaxf(v, __shfl_xor(v, off, 16));
        const float mn = fmaxf(mrow[r], v);
        al[r] = __expf(mrow[r] - mn);
        mrow[r] = mn;
        sa[0][r] = __expf(sa[0][r] - mn);
        sa[1][r] = __expf(sa[1][r] - mn);
        float s = sa[0][r] + sa[1][r];
#pragma unroll
        for (int off = 8; off >= 1; off >>= 1) s += __shfl_xor(s, off, 16);
        lsum[r] = lsum[r] * al[r] + s;
      }
      // P -> LDS (C/D layout) -> A-fragment layout
      unsigned short* pb = Ps + w * 512;
#pragma unroll
      for (int cf = 0; cf < 2; ++cf)
#pragma unroll
        for (int r = 0; r < 4; ++r)
          pb[(lg + r) * 32 + cf * 16 + lr] = f2bf(sa[cf][r]);
#pragma unroll
      for (int d = 0; d < 8; ++d)
#pragma unroll
        for (int r = 0; r < 4; ++r) oacc[d][r] *= al[r];
      bf16x8 pa = *(const bf16x8*)&pb[lr * 32 + lk];
#pragma unroll
      for (int d = 0; d < 8; ++d) {
        bf16x8 vf = *(const bf16x8*)&Vs[(d * 16 + lr) * 32 + lk];
        oacc[d] = __builtin_amdgcn_mfma_f32_16x16x32_bf16(pa, vf, oacc[d], 0, 0, 0);
      }
    }
    __syncthreads();
  }
  float rl[4];
#pragma unroll
  for (int r = 0; r < 4; ++r) rl[r] = 1.f / lsum[r];
#pragma unroll
  for (int d = 0; d < 8; ++d)
#pragma unroll
    for (int r = 0; r < 4; ++r)
      Ob[(size_t)(qrow + lg + r) * HIDN + h * HDIM + d * 16 + lr] = f2bf(oacc[d][r] * rl[r]);
}

extern "C" void kernel_launch(void* const* d_in, const int* in_sizes, int n_in,
                              void* d_out, int out_size, void* d_ws, size_t ws_size,
                              hipStream_t stream) {
  const float* x    = (const float*)d_in[0];
  const float* fcos = (const float*)d_in[1];
  const float* fsin = (const float*)d_in[2];
  // d_in[3] = mask: causal computed directly
  const float* wq = (const float*)d_in[4];
  const float* wk = (const float*)d_in[5];
  const float* wv = (const float*)d_in[6];
  const float* wo = (const float*)d_in[7];
  const float* wg = (const float*)d_in[8];
  const float* wu = (const float*)d_in[9];
  const float* wd = (const float*)d_in[10];
  const float* n1 = (const float*)d_in[11];
  const float* n2 = (const float*)d_in[12];
  float* out = (float*)d_out;

  const size_t HH = (size_t)HIDN * HIDN, HI = (size_t)HIDN * INTERN;
  const size_t SH = (size_t)SEQ * HIDN, SI = (size_t)SEQ * INTERN;
  unsigned short* p = (unsigned short*)d_ws;
  unsigned short* wqT = p; p += HH;
  unsigned short* wkT = p; p += HH;
  unsigned short* wvT = p; p += HH;
  unsigned short* woT = p; p += HH;
  unsigned short* wgT = p; p += HI;
  unsigned short* wuT = p; p += HI;
  unsigned short* wdT = p; p += HI;
  unsigned short* xn  = p; p += SH;   // xn, later hn
  unsigned short* qb  = p; p += SH;
  unsigned short* kb  = p; p += SH;
  unsigned short* vb  = p; p += SH;   // v, later attention out
  unsigned short* vt  = p; p += SH;
  unsigned short* ffnb = p; p += SI;
  float* hbuf = (float*)p;            // SH floats
  unsigned short* gbuf = qb;          // gate reuses dead q/k/(part of v) region

  rmsnorm_kernel<<<SEQ, 256, 0, stream>>>(x, n1, xn);
  dim3 tHH(HIDN / 32, HIDN / 32);
  transpose_f2b<<<tHH, 256, 0, stream>>>(wq, wqT, HIDN, HIDN);
  transpose_f2b<<<tHH, 256, 0, stream>>>(wk, wkT, HIDN, HIDN);
  transpose_f2b<<<tHH, 256, 0, stream>>>(wv, wvT, HIDN, HIDN);
  transpose_f2b<<<tHH, 256, 0, stream>>>(wo, woT, HIDN, HIDN);
  transpose_f2b<<<dim3(INTERN / 32, HIDN / 32), 256, 0, stream>>>(wg, wgT, HIDN, INTERN);
  transpose_f2b<<<dim3(INTERN / 32, HIDN / 32), 256, 0, stream>>>(wu, wuT, HIDN, INTERN);
  transpose_f2b<<<dim3(HIDN / 32, INTERN / 32), 256, 0, stream>>>(wd, wdT, INTERN, HIDN);

  dim3 gHH(HIDN / 128, SEQ / 128);
  gemm_bt<0><<<gHH, 256, 0, stream>>>(xn, wqT, SEQ, HIDN, HIDN, nullptr, qb, nullptr, nullptr);
  gemm_bt<0><<<gHH, 256, 0, stream>>>(xn, wkT, SEQ, HIDN, HIDN, nullptr, kb, nullptr, nullptr);
  gemm_bt<0><<<gHH, 256, 0, stream>>>(xn, wvT, SEQ, HIDN, HIDN, nullptr, vb, nullptr, nullptr);
  rope_kernel<<<SEQ, 256, 0, stream>>>(qb, fcos, fsin);
  rope_kernel<<<SEQ, 256, 0, stream>>>(kb, fcos, fsin);
  transpose_b2b<<<dim3(HIDN / 32, SEQ / 32), 256, 0, stream>>>(vb, vt, SEQ, HIDN);
  attn_kernel<<<dim3(SEQ / 64, NHEAD), 256, 0, stream>>>(qb, kb, vt, vb);
  gemm_bt<1><<<gHH, 256, 0, stream>>>(vb, woT, SEQ, HIDN, HIDN, hbuf, nullptr, x, nullptr);
  rmsnorm_kernel<<<SEQ, 256, 0, stream>>>(hbuf, n2, xn);
  dim3 gHI(INTERN / 128, SEQ / 128);
  gemm_bt<0><<<gHI, 256, 0, stream>>>(xn, wgT, SEQ, INTERN, HIDN, nullptr, gbuf, nullptr, nullptr);
  gemm_bt<2><<<gHI, 256, 0, stream>>>(xn, wuT, SEQ, INTERN, HIDN, nullptr, ffnb, nullptr, gbuf);
  gemm_bt<1><<<gHH, 256, 0, stream>>>(ffnb, wdT, SEQ, HIDN, INTERN, out, nullptr, hbuf, nullptr);
}

// Round 2
// 1141.236 us; speedup vs baseline: 1.1299x; 1.1299x over previous
//
#include <hip/hip_runtime.h>
#include <hip/hip_bf16.h>
#include <cstdint>
#include <cstddef>

#define HIDN 2048
#define NHEAD 16
#define HDIM 128
#define INTERN 5632
#define SEQ 4096

typedef __bf16 bf16x8 __attribute__((ext_vector_type(8)));
typedef float f32x4 __attribute__((ext_vector_type(4)));
typedef unsigned short u16x8 __attribute__((ext_vector_type(8)));

__device__ __forceinline__ float bf2f(unsigned short u) {
  unsigned v = ((unsigned)u) << 16; float f; __builtin_memcpy(&f, &v, 4); return f;
}
__device__ __forceinline__ unsigned short f2bf(float f) {
  unsigned u; __builtin_memcpy(&u, &f, 4);
  unsigned r = 0x7FFFu + ((u >> 16) & 1u);
  return (unsigned short)((u + r) >> 16);
}
// async global->LDS, 16B per lane. dst must be wave-linear: base + lane*16B.
__device__ __forceinline__ void gl_lds16(const unsigned short* g, unsigned short* l) {
  __builtin_amdgcn_global_load_lds((unsigned int __attribute__((address_space(1)))*)g,
                                   (unsigned int __attribute__((address_space(3)))*)l,
                                   16, 0, 0);
}

// ---------------- RMSNorm: fp32 row -> bf16 row ----------------
__global__ __launch_bounds__(256) void rmsnorm_kernel(const float* __restrict__ x,
                                                      const float* __restrict__ wgt,
                                                      unsigned short* __restrict__ out) {
  const int tid = threadIdx.x;
  const size_t base = (size_t)blockIdx.x * HIDN + tid * 8;
  f32x4 a = *(const f32x4*)(x + base);
  f32x4 b = *(const f32x4*)(x + base + 4);
  float ss = a[0]*a[0]+a[1]*a[1]+a[2]*a[2]+a[3]*a[3]
           + b[0]*b[0]+b[1]*b[1]+b[2]*b[2]+b[3]*b[3];
#pragma unroll
  for (int off = 32; off >= 1; off >>= 1) ss += __shfl_xor(ss, off, 64);
  __shared__ float red[4];
  if ((tid & 63) == 0) red[tid >> 6] = ss;
  __syncthreads();
  float tot = red[0] + red[1] + red[2] + red[3];
  float sc = 1.f / sqrtf(tot * (1.f / HIDN) + 1e-6f);
  f32x4 w0 = *(const f32x4*)(wgt + tid * 8);
  f32x4 w1 = *(const f32x4*)(wgt + tid * 8 + 4);
  u16x8 o;
#pragma unroll
  for (int i = 0; i < 4; ++i) { o[i] = f2bf(a[i] * sc * w0[i]); o[i+4] = f2bf(b[i] * sc * w1[i]); }
  *(u16x8*)(out + base) = o;
}

// ---------------- transpose fp32 [R][C] -> bf16 [C][R] ----------------
__global__ __launch_bounds__(256) void transpose_f2b(const float* __restrict__ in,
                                                     unsigned short* __restrict__ out,
                                                     int R, int C) {
  __shared__ float tile[32][33];
  const int bx = blockIdx.x * 32, by = blockIdx.y * 32;
  const int tx = threadIdx.x & 31, ty = threadIdx.x >> 5;
#pragma unroll
  for (int i = 0; i < 32; i += 8)
    tile[ty + i][tx] = in[(size_t)(by + ty + i) * C + bx + tx];
  __syncthreads();
#pragma unroll
  for (int i = 0; i < 32; i += 8)
    out[(size_t)(bx + ty + i) * R + by + tx] = f2bf(tile[tx][ty + i]);
}

// ---------------- transpose bf16 [R][C] -> bf16 [C][R] ----------------
__global__ __launch_bounds__(256) void transpose_b2b(const unsigned short* __restrict__ in,
                                                     unsigned short* __restrict__ out,
                                                     int R, int C) {
  __shared__ unsigned short tile[32][33];
  const int bx = blockIdx.x * 32, by = blockIdx.y * 32;
  const int tx = threadIdx.x & 31, ty = threadIdx.x >> 5;
#pragma unroll
  for (int i = 0; i < 32; i += 8)
    tile[ty + i][tx] = in[(size_t)(by + ty + i) * C + bx + tx];
  __syncthreads();
#pragma unroll
  for (int i = 0; i < 32; i += 8)
    out[(size_t)(bx + ty + i) * R + by + tx] = tile[tx][ty + i];
}

// ---------------- RoPE in-place on bf16 [SEQ][HIDN] ----------------
__global__ __launch_bounds__(256) void rope_kernel(unsigned short* __restrict__ v,
                                                   const float* __restrict__ cosb,
                                                   const float* __restrict__ sinb) {
  const int s = blockIdx.x, tid = threadIdx.x;
  const size_t base = (size_t)s * HIDN + tid * 8;
  u16x8 u = *(const u16x8*)(v + base);
  const int j0 = ((tid * 8) & 127) >> 1;
  const float* cr = cosb + s * 64 + j0;
  const float* sr = sinb + s * 64 + j0;
  u16x8 o;
#pragma unroll
  for (int p = 0; p < 4; ++p) {
    float re = bf2f(u[2*p]), im = bf2f(u[2*p+1]);
    float c = cr[p], sn = sr[p];
    o[2*p]   = f2bf(re * c - im * sn);
    o[2*p+1] = f2bf(re * sn + im * c);
  }
  *(u16x8*)(v + base) = o;
}

// ---------------- bf16 GEMM, m97 structure: C[M,N] = A[M,K] * Bt[N,K]^T ----------------
template<int EPI>
__global__ __launch_bounds__(256) void gemm_bt(const unsigned short* __restrict__ A,
                                               const unsigned short* __restrict__ Bt,
                                               int M, int N, int K,
                                               float* __restrict__ outF,
                                               unsigned short* __restrict__ outB,
                                               const float* __restrict__ res,
                                               const unsigned short* __restrict__ gate) {
  __shared__ unsigned short As[128 * 32];
  __shared__ unsigned short Bs[128 * 32];
  const int tid = threadIdx.x;
  const int w = tid >> 6, l = tid & 63;
  const int lr = l & 15, lk = (l >> 4) * 8;
  const int m0 = blockIdx.y * 128, n0 = blockIdx.x * 128;
  const int wm = (w >> 1) * 64, wn = (w & 1) * 64;

  f32x4 acc[4][4];
#pragma unroll
  for (int i = 0; i < 4; ++i)
#pragma unroll
    for (int j = 0; j < 4; ++j) acc[i][j] = (f32x4){0.f, 0.f, 0.f, 0.f};

  const int srow = tid >> 2, scol = (tid & 3) * 8;
  const unsigned short* a0 = A + (size_t)(m0 + srow) * K + scol;
  const unsigned short* a1 = A + (size_t)(m0 + 64 + srow) * K + scol;
  const unsigned short* b0 = Bt + (size_t)(n0 + srow) * K + scol;
  const unsigned short* b1 = Bt + (size_t)(n0 + 64 + srow) * K + scol;
  unsigned short* ad0 = As + tid * 8;
  unsigned short* ad1 = As + 2048 + tid * 8;
  unsigned short* bd0 = Bs + tid * 8;
  unsigned short* bd1 = Bs + 2048 + tid * 8;

  for (int k0 = 0; k0 < K; k0 += 32) {
    gl_lds16(a0 + k0, ad0);
    gl_lds16(a1 + k0, ad1);
    gl_lds16(b0 + k0, bd0);
    gl_lds16(b1 + k0, bd1);
    __syncthreads();
    bf16x8 af[4], bfr[4];
#pragma unroll
    for (int m = 0; m < 4; ++m) af[m] = *(const bf16x8*)&As[(wm + m * 16 + lr) * 32 + lk];
#pragma unroll
    for (int n = 0; n < 4; ++n) bfr[n] = *(const bf16x8*)&Bs[(wn + n * 16 + lr) * 32 + lk];
#pragma unroll
    for (int m = 0; m < 4; ++m)
#pragma unroll
      for (int n = 0; n < 4; ++n)
        acc[m][n] = __builtin_amdgcn_mfma_f32_16x16x32_bf16(af[m], bfr[n], acc[m][n], 0, 0, 0);
    __syncthreads();
  }

#pragma unroll
  for (int m = 0; m < 4; ++m)
#pragma unroll
    for (int n = 0; n < 4; ++n)
#pragma unroll
      for (int r = 0; r < 4; ++r) {
        const int row = m0 + wm + m * 16 + (l >> 4) * 4 + r;
        const int col = n0 + wn + n * 16 + lr;
        const size_t idx = (size_t)row * N + col;
        float v = acc[m][n][r];
        if (EPI == 0) {
          outB[idx] = f2bf(v);
        } else if (EPI == 1) {
          outF[idx] = res[idx] + v;
        } else {
          float g = bf2f(gate[idx]);
          float s = g / (1.f + __expf(-g));
          outB[idx] = f2bf(s * v);
        }
      }
}

// ---------------- causal flash attention, KVBLK=64, dbuf, XOR-swizzled LDS ----------------
// Q,K: bf16 [SEQ][HIDN] (rope'd). Vt: bf16 [HIDN][SEQ]. Ob: bf16 [SEQ][HIDN].
// Block: (q-tile of 64, head). 4 waves x 16 q-rows each.
__global__ __launch_bounds__(256) void attn_kernel(const unsigned short* __restrict__ Q,
                                                   const unsigned short* __restrict__ Kb,
                                                   const unsigned short* __restrict__ Vt,
                                                   unsigned short* __restrict__ Ob) {
  __shared__ unsigned short Ks[2][64 * 128];   // [kv][d], 256B rows, swizzled
  __shared__ unsigned short Vs[2][128 * 64];   // [d][kv], 128B rows, swizzled
  __shared__ unsigned short Ps[4][16 * 64];    // per-wave [q][kv], 128B rows, swizzled
  const int tid = threadIdx.x, w = tid >> 6, l = tid & 63;
  const int lr = l & 15, lk = (l >> 4) * 8, lg = (l >> 4) * 4;
  const int h = blockIdx.y;
  const int qb0 = (gridDim.x - 1 - blockIdx.x) * 64;   // heaviest blocks first
  const int qrow = qb0 + w * 16;
  const int sw = (lr & 7) << 3;   // element-index XOR for 16B-granule swizzle

  bf16x8 qf[4];
#pragma unroll
  for (int d = 0; d < 4; ++d)
    qf[d] = *(const bf16x8*)(Q + (size_t)(qrow + lr) * HIDN + h * HDIM + d * 32 + lk);

  float mrow[4] = {-1e30f, -1e30f, -1e30f, -1e30f};
  float lsum[4] = {0.f, 0.f, 0.f, 0.f};
  f32x4 oacc[8];
#pragma unroll
  for (int d = 0; d < 8; ++d) oacc[d] = (f32x4){0.f, 0.f, 0.f, 0.f};

  // staging geometry (pre-swizzled global source, linear LDS dest: rule #21)
  const int krow = tid >> 4, kc2 = (tid & 15) * 16;   // K: 16 rows/issue, 256B rows
  const int vrow = tid >> 3, vc2 = (tid & 7) * 16;    // V: 32 rows/issue, 128B rows
  const int nt = qb0 / 64 + 1;

#define STAGE(T, B)                                                                        \
  {                                                                                        \
    const int kv0_ = (T) * 64;                                                             \
    _Pragma("unroll")                                                                      \
    for (int i = 0; i < 4; ++i) {                                                          \
      const int row = i * 16 + krow;                                                       \
      gl_lds16(Kb + (size_t)(kv0_ + row) * HIDN + h * HDIM + ((kc2 ^ ((row & 7) << 4)) >> 1), \
               &Ks[B][i * 2048 + tid * 8]);                                                \
    }                                                                                      \
    _Pragma("unroll")                                                                      \
    for (int i = 0; i < 4; ++i) {                                                          \
      const int row = i * 32 + vrow;                                                       \
      gl_lds16(Vt + (size_t)(h * HDIM + row) * SEQ + kv0_ + ((vc2 ^ ((row & 7) << 4)) >> 1), \
               &Vs[B][i * 2048 + tid * 8]);                                                \
    }                                                                                      \
  }

  STAGE(0, 0);
  __syncthreads();   // implicit vmcnt(0) drain covers the staging

  for (int t = 0; t < nt; ++t) {
    const int cur = t & 1;
    if (t + 1 < nt) STAGE(t + 1, cur ^ 1);   // prefetch overlaps compute (T3-minimum)
    const int kv0 = t * 64;

    // ---- QK^T: sa[cf] covers k-cols cf*16..+15 ----
    f32x4 sa[4];
#pragma unroll
    for (int cf = 0; cf < 4; ++cf) sa[cf] = (f32x4){0.f, 0.f, 0.f, 0.f};
#pragma unroll
    for (int cf = 0; cf < 4; ++cf)
#pragma unroll
      for (int d = 0; d < 4; ++d) {
        bf16x8 kf = *(const bf16x8*)&Ks[cur][(cf * 16 + lr) * 128 + ((d * 32 + lk) ^ sw)];
        sa[cf] = __builtin_amdgcn_mfma_f32_16x16x32_bf16(qf[d], kf, sa[cf], 0, 0, 0);
      }

    // ---- scale + causal mask (diagonal tile only) ----
    const bool diag = (t == nt - 1);
#pragma unroll
    for (int cf = 0; cf < 4; ++cf)
#pragma unroll
      for (int r = 0; r < 4; ++r) {
        float v = sa[cf][r] * 0.08838834764831845f;
        if (diag) {
          const int qi = qrow + lg + r;
          const int ki = kv0 + cf * 16 + lr;
          v = (ki > qi) ? -1e30f : v;
        }
        sa[cf][r] = v;
      }

    // ---- row maxima (16-lane shuffle reduce) ----
    float vmax[4], al[4];
#pragma unroll
    for (int r = 0; r < 4; ++r) {
      float v = fmaxf(fmaxf(sa[0][r], sa[1][r]), fmaxf(sa[2][r], sa[3][r]));
#pragma unroll
      for (int off = 8; off >= 1; off >>= 1) v = fmaxf(v, __shfl_xor(v, off, 16));
      vmax[r] = v;
    }
    // T13 defer-max: skip O-rescale when max growth <= 8
    int ok = (vmax[0] <= mrow[0] + 8.f) & (vmax[1] <= mrow[1] + 8.f) &
             (vmax[2] <= mrow[2] + 8.f) & (vmax[3] <= mrow[3] + 8.f);
    if (__all(ok)) {
#pragma unroll
      for (int r = 0; r < 4; ++r) al[r] = 1.f;
    } else {
#pragma unroll
      for (int r = 0; r < 4; ++r) {
        const float mn = fmaxf(mrow[r], vmax[r]);
        al[r] = __expf(mrow[r] - mn);
        mrow[r] = mn;
      }
#pragma unroll
      for (int d = 0; d < 8; ++d)
#pragma unroll
        for (int r = 0; r < 4; ++r) oacc[d][r] *= al[r];
    }

    // ---- P = exp(S - m), row sums ----
#pragma unroll
    for (int r = 0; r < 4; ++r) {
      float s = 0.f;
#pragma unroll
      for (int cf = 0; cf < 4; ++cf) {
        const float pv = __expf(sa[cf][r] - mrow[r]);
        sa[cf][r] = pv;
        s += pv;
      }
#pragma unroll
      for (int off = 8; off >= 1; off >>= 1) s += __shfl_xor(s, off, 16);
      lsum[r] = lsum[r] * al[r] + s;
    }

    // ---- P -> LDS (swizzled) -> A-fragments ----
    unsigned short* pb = Ps[w];
#pragma unroll
    for (int cf = 0; cf < 4; ++cf)
#pragma unroll
      for (int r = 0; r < 4; ++r) {
        const int row = lg + r, col = cf * 16 + lr;
        pb[row * 64 + (col ^ ((row & 7) << 3))] = f2bf(sa[cf][r]);
      }
    bf16x8 pa0 = *(const bf16x8*)&pb[lr * 64 + (lk ^ sw)];
    bf16x8 pa1 = *(const bf16x8*)&pb[lr * 64 + ((32 + lk) ^ sw)];

    // ---- PV ----
#pragma unroll
    for (int d = 0; d < 8; ++d) {
      bf16x8 vf0 = *(const bf16x8*)&Vs[cur][(d * 16 + lr) * 64 + (lk ^ sw)];
      bf16x8 vf1 = *(const bf16x8*)&Vs[cur][(d * 16 + lr) * 64 + ((32 + lk) ^ sw)];
      oacc[d] = __builtin_amdgcn_mfma_f32_16x16x32_bf16(pa0, vf0, oacc[d], 0, 0, 0);
      oacc[d] = __builtin_amdgcn_mfma_f32_16x16x32_bf16(pa1, vf1, oacc[d], 0, 0, 0);
    }
    __syncthreads();   // one barrier per tile: drains prefetch + protects buffers
  }
#undef STAGE

  float rl[4];
#pragma unroll
  for (int r = 0; r < 4; ++r) rl[r] = 1.f / lsum[r];
#pragma unroll
  for (int d = 0; d < 8; ++d)
#pragma unroll
    for (int r = 0; r < 4; ++r)
      Ob[(size_t)(qrow + lg + r) * HIDN + h * HDIM + d * 16 + lr] = f2bf(oacc[d][r] * rl[r]);
}

extern "C" void kernel_launch(void* const* d_in, const int* in_sizes, int n_in,
                              void* d_out, int out_size, void* d_ws, size_t ws_size,
                              hipStream_t stream) {
  const float* x    = (const float*)d_in[0];
  const float* fcos = (const float*)d_in[1];
  const float* fsin = (const float*)d_in[2];
  // d_in[3] = mask: causal computed directly
  const float* wq = (const float*)d_in[4];
  const float* wk = (const float*)d_in[5];
  const float* wv = (const float*)d_in[6];
  const float* wo = (const float*)d_in[7];
  const float* wg = (const float*)d_in[8];
  const float* wu = (const float*)d_in[9];
  const float* wd = (const float*)d_in[10];
  const float* n1 = (const float*)d_in[11];
  const float* n2 = (const float*)d_in[12];
  float* out = (float*)d_out;

  const size_t HH = (size_t)HIDN * HIDN, HI = (size_t)HIDN * INTERN;
  const size_t SH = (size_t)SEQ * HIDN, SI = (size_t)SEQ * INTERN;
  unsigned short* p = (unsigned short*)d_ws;
  unsigned short* wqT = p; p += HH;
  unsigned short* wkT = p; p += HH;
  unsigned short* wvT = p; p += HH;
  unsigned short* woT = p; p += HH;
  unsigned short* wgT = p; p += HI;
  unsigned short* wuT = p; p += HI;
  unsigned short* wdT = p; p += HI;
  unsigned short* xn  = p; p += SH;   // xn, later hn
  unsigned short* qb  = p; p += SH;
  unsigned short* kb  = p; p += SH;
  unsigned short* vb  = p; p += SH;   // v, later attention out
  unsigned short* vt  = p; p += SH;
  unsigned short* ffnb = p; p += SI;
  float* hbuf = (float*)p;            // SH floats
  unsigned short* gbuf = qb;          // gate reuses dead q/k/(part of v) region

  rmsnorm_kernel<<<SEQ, 256, 0, stream>>>(x, n1, xn);
  dim3 tHH(HIDN / 32, HIDN / 32);
  transpose_f2b<<<tHH, 256, 0, stream>>>(wq, wqT, HIDN, HIDN);
  transpose_f2b<<<tHH, 256, 0, stream>>>(wk, wkT, HIDN, HIDN);
  transpose_f2b<<<tHH, 256, 0, stream>>>(wv, wvT, HIDN, HIDN);
  transpose_f2b<<<tHH, 256, 0, stream>>>(wo, woT, HIDN, HIDN);
  transpose_f2b<<<dim3(INTERN / 32, HIDN / 32), 256, 0, stream>>>(wg, wgT, HIDN, INTERN);
  transpose_f2b<<<dim3(INTERN / 32, HIDN / 32), 256, 0, stream>>>(wu, wuT, HIDN, INTERN);
  transpose_f2b<<<dim3(HIDN / 32, INTERN / 32), 256, 0, stream>>>(wd, wdT, INTERN, HIDN);

  dim3 gHH(HIDN / 128, SEQ / 128);
  gemm_bt<0><<<gHH, 256, 0, stream>>>(xn, wqT, SEQ, HIDN, HIDN, nullptr, qb, nullptr, nullptr);
  gemm_bt<0><<<gHH, 256, 0, stream>>>(xn, wkT, SEQ, HIDN, HIDN, nullptr, kb, nullptr, nullptr);
  gemm_bt<0><<<gHH, 256, 0, stream>>>(xn, wvT, SEQ, HIDN, HIDN, nullptr, vb, nullptr, nullptr);
  rope_kernel<<<SEQ, 256, 0, stream>>>(qb, fcos, fsin);
  rope_kernel<<<SEQ, 256, 0, stream>>>(kb, fcos, fsin);
  transpose_b2b<<<dim3(HIDN / 32, SEQ / 32), 256, 0, stream>>>(vb, vt, SEQ, HIDN);
  attn_kernel<<<dim3(SEQ / 64, NHEAD), 256, 0, stream>>>(qb, kb, vt, vb);
  gemm_bt<1><<<gHH, 256, 0, stream>>>(vb, woT, SEQ, HIDN, HIDN, hbuf, nullptr, x, nullptr);
  rmsnorm_kernel<<<SEQ, 256, 0, stream>>>(hbuf, n2, xn);
  dim3 gHI(INTERN / 128, SEQ / 128);
  gemm_bt<0><<<gHI, 256, 0, stream>>>(xn, wgT, SEQ, INTERN, HIDN, nullptr, gbuf, nullptr, nullptr);
  gemm_bt<2><<<gHI, 256, 0, stream>>>(xn, wuT, SEQ, INTERN, HIDN, nullptr, ffnb, nullptr, gbuf);
  gemm_bt<1><<<gHH, 256, 0, stream>>>(ffnb, wdT, SEQ, HIDN, INTERN, out, nullptr, hbuf, nullptr);
}

// Round 4
// 1101.911 us; speedup vs baseline: 1.1703x; 1.0357x over previous
//
#include <hip/hip_runtime.h>
#include <hip/hip_bf16.h>
#include <cstdint>
#include <cstddef>

#define HIDN 2048
#define NHEAD 16
#define HDIM 128
#define INTERN 5632
#define SEQ 4096

typedef __bf16 bf16x8 __attribute__((ext_vector_type(8)));
typedef float f32x4 __attribute__((ext_vector_type(4)));
typedef float f32x16 __attribute__((ext_vector_type(16)));
typedef unsigned short u16x8 __attribute__((ext_vector_type(8)));

__device__ __forceinline__ float bf2f(unsigned short u) {
  unsigned v = ((unsigned)u) << 16; float f; __builtin_memcpy(&f, &v, 4); return f;
}
__device__ __forceinline__ unsigned short f2bf(float f) {
  unsigned u; __builtin_memcpy(&u, &f, 4);
  unsigned r = 0x7FFFu + ((u >> 16) & 1u);
  return (unsigned short)((u + r) >> 16);
}
// async global->LDS, 16B per lane. dst must be wave-linear: base + lane*16B.
__device__ __forceinline__ void gl_lds16(const unsigned short* g, unsigned short* l) {
  __builtin_amdgcn_global_load_lds((unsigned int __attribute__((address_space(1)))*)g,
                                   (unsigned int __attribute__((address_space(3)))*)l,
                                   16, 0, 0);
}
// pack two f32 -> one u32 of 2x bf16 (lo in low half)
__device__ __forceinline__ unsigned cvtpk(float lo, float hi) {
  unsigned r; asm("v_cvt_pk_bf16_f32 %0, %1, %2" : "=v"(r) : "v"(lo), "v"(hi)); return r;
}
// swap a.hi-lanes <-> b.lo-lanes: a' = {a.lo, b.lo}, b' = {a.hi, b.hi}
__device__ __forceinline__ void plswap(unsigned& a, unsigned& b) {
  asm("v_permlane32_swap_b32 %0, %1" : "+v"(a), "+v"(b));
}
__device__ __forceinline__ bf16x8 mk_pa(unsigned w0, unsigned w1, unsigned w2, unsigned w3) {
  union { unsigned u[4]; bf16x8 v; } t; t.u[0] = w0; t.u[1] = w1; t.u[2] = w2; t.u[3] = w3; return t.v;
}

// ---------------- RMSNorm: fp32 row -> bf16 row ----------------
__global__ __launch_bounds__(256) void rmsnorm_kernel(const float* __restrict__ x,
                                                      const float* __restrict__ wgt,
                                                      unsigned short* __restrict__ out) {
  const int tid = threadIdx.x;
  const size_t base = (size_t)blockIdx.x * HIDN + tid * 8;
  f32x4 a = *(const f32x4*)(x + base);
  f32x4 b = *(const f32x4*)(x + base + 4);
  float ss = a[0]*a[0]+a[1]*a[1]+a[2]*a[2]+a[3]*a[3]
           + b[0]*b[0]+b[1]*b[1]+b[2]*b[2]+b[3]*b[3];
#pragma unroll
  for (int off = 32; off >= 1; off >>= 1) ss += __shfl_xor(ss, off, 64);
  __shared__ float red[4];
  if ((tid & 63) == 0) red[tid >> 6] = ss;
  __syncthreads();
  float tot = red[0] + red[1] + red[2] + red[3];
  float sc = 1.f / sqrtf(tot * (1.f / HIDN) + 1e-6f);
  f32x4 w0 = *(const f32x4*)(wgt + tid * 8);
  f32x4 w1 = *(const f32x4*)(wgt + tid * 8 + 4);
  u16x8 o;
#pragma unroll
  for (int i = 0; i < 4; ++i) { o[i] = f2bf(a[i] * sc * w0[i]); o[i+4] = f2bf(b[i] * sc * w1[i]); }
  *(u16x8*)(out + base) = o;
}

// ---------------- transpose fp32 [R][C] -> bf16 [C][R] ----------------
__global__ __launch_bounds__(256) void transpose_f2b(const float* __restrict__ in,
                                                     unsigned short* __restrict__ out,
                                                     int R, int C) {
  __shared__ float tile[32][33];
  const int bx = blockIdx.x * 32, by = blockIdx.y * 32;
  const int tx = threadIdx.x & 31, ty = threadIdx.x >> 5;
#pragma unroll
  for (int i = 0; i < 32; i += 8)
    tile[ty + i][tx] = in[(size_t)(by + ty + i) * C + bx + tx];
  __syncthreads();
#pragma unroll
  for (int i = 0; i < 32; i += 8)
    out[(size_t)(bx + ty + i) * R + by + tx] = f2bf(tile[tx][ty + i]);
}

// ---------------- transpose bf16 [R][C] -> bf16 [C][R] ----------------
__global__ __launch_bounds__(256) void transpose_b2b(const unsigned short* __restrict__ in,
                                                     unsigned short* __restrict__ out,
                                                     int R, int C) {
  __shared__ unsigned short tile[32][33];
  const int bx = blockIdx.x * 32, by = blockIdx.y * 32;
  const int tx = threadIdx.x & 31, ty = threadIdx.x >> 5;
#pragma unroll
  for (int i = 0; i < 32; i += 8)
    tile[ty + i][tx] = in[(size_t)(by + ty + i) * C + bx + tx];
  __syncthreads();
#pragma unroll
  for (int i = 0; i < 32; i += 8)
    out[(size_t)(bx + ty + i) * R + by + tx] = tile[tx][ty + i];
}

// ---------------- RoPE in-place on bf16 [SEQ][HIDN] ----------------
__global__ __launch_bounds__(256) void rope_kernel(unsigned short* __restrict__ v,
                                                   const float* __restrict__ cosb,
                                                   const float* __restrict__ sinb) {
  const int s = blockIdx.x, tid = threadIdx.x;
  const size_t base = (size_t)s * HIDN + tid * 8;
  u16x8 u = *(const u16x8*)(v + base);
  const int j0 = ((tid * 8) & 127) >> 1;
  const float* cr = cosb + s * 64 + j0;
  const float* sr = sinb + s * 64 + j0;
  u16x8 o;
#pragma unroll
  for (int p = 0; p < 4; ++p) {
    float re = bf2f(u[2*p]), im = bf2f(u[2*p+1]);
    float c = cr[p], sn = sr[p];
    o[2*p]   = f2bf(re * c - im * sn);
    o[2*p+1] = f2bf(re * sn + im * c);
  }
  *(u16x8*)(v + base) = o;
}

// ---------------- bf16 GEMM, m97 structure: C[M,N] = A[M,K] * Bt[N,K]^T ----------------
template<int EPI>
__global__ __launch_bounds__(256) void gemm_bt(const unsigned short* __restrict__ A,
                                               const unsigned short* __restrict__ Bt,
                                               int M, int N, int K,
                                               float* __restrict__ outF,
                                               unsigned short* __restrict__ outB,
                                               const float* __restrict__ res,
                                               const unsigned short* __restrict__ gate) {
  __shared__ unsigned short As[128 * 32];
  __shared__ unsigned short Bs[128 * 32];
  const int tid = threadIdx.x;
  const int w = tid >> 6, l = tid & 63;
  const int lr = l & 15, lk = (l >> 4) * 8;
  const int m0 = blockIdx.y * 128, n0 = blockIdx.x * 128;
  const int wm = (w >> 1) * 64, wn = (w & 1) * 64;

  f32x4 acc[4][4];
#pragma unroll
  for (int i = 0; i < 4; ++i)
#pragma unroll
    for (int j = 0; j < 4; ++j) acc[i][j] = (f32x4){0.f, 0.f, 0.f, 0.f};

  const int srow = tid >> 2, scol = (tid & 3) * 8;
  const unsigned short* a0 = A + (size_t)(m0 + srow) * K + scol;
  const unsigned short* a1 = A + (size_t)(m0 + 64 + srow) * K + scol;
  const unsigned short* b0 = Bt + (size_t)(n0 + srow) * K + scol;
  const unsigned short* b1 = Bt + (size_t)(n0 + 64 + srow) * K + scol;
  unsigned short* ad0 = As + tid * 8;
  unsigned short* ad1 = As + 2048 + tid * 8;
  unsigned short* bd0 = Bs + tid * 8;
  unsigned short* bd1 = Bs + 2048 + tid * 8;

  for (int k0 = 0; k0 < K; k0 += 32) {
    gl_lds16(a0 + k0, ad0);
    gl_lds16(a1 + k0, ad1);
    gl_lds16(b0 + k0, bd0);
    gl_lds16(b1 + k0, bd1);
    __syncthreads();
    bf16x8 af[4], bfr[4];
#pragma unroll
    for (int m = 0; m < 4; ++m) af[m] = *(const bf16x8*)&As[(wm + m * 16 + lr) * 32 + lk];
#pragma unroll
    for (int n = 0; n < 4; ++n) bfr[n] = *(const bf16x8*)&Bs[(wn + n * 16 + lr) * 32 + lk];
#pragma unroll
    for (int m = 0; m < 4; ++m)
#pragma unroll
      for (int n = 0; n < 4; ++n)
        acc[m][n] = __builtin_amdgcn_mfma_f32_16x16x32_bf16(af[m], bfr[n], acc[m][n], 0, 0, 0);
    __syncthreads();
  }

#pragma unroll
  for (int m = 0; m < 4; ++m)
#pragma unroll
    for (int n = 0; n < 4; ++n)
#pragma unroll
      for (int r = 0; r < 4; ++r) {
        const int row = m0 + wm + m * 16 + (l >> 4) * 4 + r;
        const int col = n0 + wn + n * 16 + lr;
        const size_t idx = (size_t)row * N + col;
        float v = acc[m][n][r];
        if (EPI == 0) {
          outB[idx] = f2bf(v);
        } else if (EPI == 1) {
          outF[idx] = res[idx] + v;
        } else {
          float g = bf2f(gate[idx]);
          float s = g / (1.f + __expf(-g));
          outB[idx] = f2bf(s * v);
        }
      }
}

// ---------------- causal flash attention v3: swapped QK^T, in-register softmax ----------------
// 4 warps x 32 q-rows (QBLK=128), KVBLK=64, dbuf K/V in LDS, no P round-trip.
// Q,K: bf16 [SEQ][HIDN] (rope'd). Vt: bf16 [HIDN][SEQ]. Ob: bf16 [SEQ][HIDN].
// S^T = mfma(K,Q): lane holds q-col = lane&31, kv rows (reg&3)+8*(reg>>2)+4*(lane>>5).
__global__ __launch_bounds__(256) void attn_kernel(const unsigned short* __restrict__ Q,
                                                   const unsigned short* __restrict__ Kb,
                                                   const unsigned short* __restrict__ Vt,
                                                   unsigned short* __restrict__ Ob) {
  __shared__ unsigned short Ks[2][64 * 128];   // [kv][d], 256B rows, (row&15)<<4 swizzle
  __shared__ unsigned short Vs[2][128 * 64];   // [d][kv], 128B rows, (row&7)<<4 swizzle
  __shared__ float alS[4][32];                 // per-warp q-indexed gather scratch
  const int tid = threadIdx.x, w = tid >> 6, l = tid & 63;
  const int lq = l & 31, hi = l >> 5;
  const int h = blockIdx.y;
  const int qb0 = ((int)gridDim.x - 1 - (int)blockIdx.x) * 128;   // heavy blocks first
  const int qw0 = qb0 + w * 32;

  // Q as B-operand: lane holds q-col = lq, d = c*16 + hi*8 .. +7
  bf16x8 qf[8];
#pragma unroll
  for (int c = 0; c < 8; ++c)
    qf[c] = *(const bf16x8*)(Q + (size_t)(qw0 + lq) * HIDN + h * HDIM + c * 16 + hi * 8);

  float m2 = -1e30f, lsum = 0.f;   // per-lane: running max / denom for q = lq (log2 domain)
  f32x16 o[4];
#pragma unroll
  for (int dc = 0; dc < 4; ++dc) o[dc] = (f32x16){};

  const int krow = tid >> 4, kc2 = (tid & 15) * 16;   // K stage: 256B rows, byte col
  const int vrow = tid >> 3, vc2 = (tid & 7) * 16;    // V stage: 128B rows, byte col
  const int nt = qb0 / 64 + 2;

#define STAGE(T, B)                                                                          \
  {                                                                                          \
    const int kv0_ = (T) * 64;                                                               \
    _Pragma("unroll")                                                                        \
    for (int i = 0; i < 4; ++i) {                                                            \
      const int row = i * 16 + krow;                                                         \
      gl_lds16(Kb + (size_t)(kv0_ + row) * HIDN + h * HDIM + ((kc2 ^ ((row & 15) << 4)) >> 1), \
               &Ks[B][i * 2048 + tid * 8]);                                                  \
    }                                                                                        \
    _Pragma("unroll")                                                                        \
    for (int i = 0; i < 4; ++i) {                                                            \
      const int row = i * 32 + vrow;                                                         \
      gl_lds16(Vt + (size_t)(h * HDIM + row) * SEQ + kv0_ + ((vc2 ^ ((row & 7) << 4)) >> 1),   \
               &Vs[B][i * 2048 + tid * 8]);                                                  \
    }                                                                                        \
  }
#define LDK(row_, c_) (*(const bf16x8*)&Ks[cur][(row_) * 128 + ((((c_) * 32 + hi * 16) ^ (((row_) & 15) << 4)) >> 1)])
#define LDV(row_, ks_) (*(const bf16x8*)&Vs[cur][(row_) * 64 + ((((ks_) * 32 + hi * 16) ^ (((row_) & 7) << 4)) >> 1)])

  STAGE(0, 0);
  __syncthreads();

  for (int t = 0; t < nt; ++t) {
    const int cur = t & 1, kv0 = t * 64;
    if (t + 1 < nt) STAGE(t + 1, cur ^ 1);   // prefetch overlaps compute

    if (kv0 <= qw0 + 31) {   // warp-uniform: skip fully-masked tiles
      // ---- QK^T (swapped): s0 = kv 0..31, s1 = kv 32..63 of this tile ----
      f32x16 s0 = {}, s1 = {};
#pragma unroll
      for (int c = 0; c < 8; ++c) {
        s0 = __builtin_amdgcn_mfma_f32_32x32x16_bf16(LDK(lq, c), qf[c], s0, 0, 0, 0);
        s1 = __builtin_amdgcn_mfma_f32_32x32x16_bf16(LDK(32 + lq, c), qf[c], s1, 0, 0, 0);
      }
      // ---- scale into exp2 domain; causal mask on diagonal-overlap tiles ----
      const float SC2 = 0.08838834764831845f * 1.44269504088896f;
#pragma unroll
      for (int r = 0; r < 16; ++r) { s0[r] *= SC2; s1[r] *= SC2; }
      if (kv0 + 63 > qw0) {   // FIX: any kv in tile can exceed some q in warp
        const int qi = qw0 + lq;
#pragma unroll
        for (int r = 0; r < 16; ++r) {
          const int kvr = kv0 + (r & 3) + 8 * (r >> 2) + 4 * hi;
          if (kvr > qi) s0[r] = -1e30f;
          if (kvr + 32 > qi) s1[r] = -1e30f;
        }
      }
      // ---- row max: 31 in-reg + 1 cross-half exchange ----
      float vm = s0[0];
#pragma unroll
      for (int r = 1; r < 16; ++r) vm = fmaxf(vm, s0[r]);
#pragma unroll
      for (int r = 0; r < 16; ++r) vm = fmaxf(vm, s1[r]);
      vm = fmaxf(vm, __shfl_xor(vm, 32, 64));
      // ---- T13 defer-max: rescale only when max grows > 8 nats (11.54 bits) ----
      float al = 1.f;
      if (!__all(vm <= m2 + 11.54f)) {
        const float mn = fmaxf(m2, vm);
        al = exp2f(m2 - mn);
        m2 = mn;
        if (l < 32) alS[w][l] = al;
#pragma unroll
        for (int r = 0; r < 16; ++r) {
          const float a = alS[w][(r & 3) + 8 * (r >> 2) + 4 * hi];
          o[0][r] *= a; o[1][r] *= a; o[2][r] *= a; o[3][r] *= a;
        }
      }
      // ---- P = exp2(s - m); row sum; pack to PV A-fragments in-register (T12) ----
      float p[32];
#pragma unroll
      for (int r = 0; r < 16; ++r) { p[r] = exp2f(s0[r] - m2); p[16 + r] = exp2f(s1[r] - m2); }
      float rsum = 0.f;
#pragma unroll
      for (int r = 0; r < 32; ++r) rsum += p[r];
      lsum = lsum * al + (rsum + __shfl_xor(rsum, 32, 64));
      bf16x8 pa[4];
#pragma unroll
      for (int hh = 0; hh < 2; ++hh) {
        unsigned ua[8];
#pragma unroll
        for (int i = 0; i < 8; ++i) ua[i] = cvtpk(p[hh * 16 + 2 * i], p[hh * 16 + 2 * i + 1]);
        plswap(ua[0], ua[2]); plswap(ua[1], ua[3]);
        plswap(ua[4], ua[6]); plswap(ua[5], ua[7]);
        pa[hh * 2]     = mk_pa(ua[0], ua[1], ua[2], ua[3]);
        pa[hh * 2 + 1] = mk_pa(ua[4], ua[5], ua[6], ua[7]);
      }
      // ---- PV: O[q][d] += P[q][kv] * V[kv][d] ----
#pragma unroll
      for (int dc = 0; dc < 4; ++dc) {
        const int vr = dc * 32 + lq;
#pragma unroll
        for (int ks = 0; ks < 4; ++ks)
          o[dc] = __builtin_amdgcn_mfma_f32_32x32x16_bf16(pa[ks], LDV(vr, ks), o[dc], 0, 0, 0);
      }
    }
    __syncthreads();
  }
#undef STAGE
#undef LDK
#undef LDV

  // ---- normalize (1/lsum gather) + store ----
  if (l < 32) alS[w][l] = 1.f / lsum;
#pragma unroll
  for (int r = 0; r < 16; ++r) {
    const int q = (r & 3) + 8 * (r >> 2) + 4 * hi;
    const float rr = alS[w][q];
    const size_t rowb = (size_t)(qw0 + q) * HIDN + h * HDIM + lq;
    Ob[rowb]      = f2bf(o[0][r] * rr);
    Ob[rowb + 32] = f2bf(o[1][r] * rr);
    Ob[rowb + 64] = f2bf(o[2][r] * rr);
    Ob[rowb + 96] = f2bf(o[3][r] * rr);
  }
}

extern "C" void kernel_launch(void* const* d_in, const int* in_sizes, int n_in,
                              void* d_out, int out_size, void* d_ws, size_t ws_size,
                              hipStream_t stream) {
  const float* x    = (const float*)d_in[0];
  const float* fcos = (const float*)d_in[1];
  const float* fsin = (const float*)d_in[2];
  // d_in[3] = mask: causal computed directly
  const float* wq = (const float*)d_in[4];
  const float* wk = (const float*)d_in[5];
  const float* wv = (const float*)d_in[6];
  const float* wo = (const float*)d_in[7];
  const float* wg = (const float*)d_in[8];
  const float* wu = (const float*)d_in[9];
  const float* wd = (const float*)d_in[10];
  const float* n1 = (const float*)d_in[11];
  const float* n2 = (const float*)d_in[12];
  float* out = (float*)d_out;

  const size_t HH = (size_t)HIDN * HIDN, HI = (size_t)HIDN * INTERN;
  const size_t SH = (size_t)SEQ * HIDN, SI = (size_t)SEQ * INTERN;
  unsigned short* p = (unsigned short*)d_ws;
  unsigned short* wqT = p; p += HH;
  unsigned short* wkT = p; p += HH;
  unsigned short* wvT = p; p += HH;
  unsigned short* woT = p; p += HH;
  unsigned short* wgT = p; p += HI;
  unsigned short* wuT = p; p += HI;
  unsigned short* wdT = p; p += HI;
  unsigned short* xn  = p; p += SH;   // xn, later hn
  unsigned short* qb  = p; p += SH;
  unsigned short* kb  = p; p += SH;
  unsigned short* vb  = p; p += SH;   // v, later attention out
  unsigned short* vt  = p; p += SH;
  unsigned short* ffnb = p; p += SI;
  float* hbuf = (float*)p;            // SH floats
  unsigned short* gbuf = qb;          // gate reuses dead q/k/(part of v) region

  rmsnorm_kernel<<<SEQ, 256, 0, stream>>>(x, n1, xn);
  dim3 tHH(HIDN / 32, HIDN / 32);
  transpose_f2b<<<tHH, 256, 0, stream>>>(wq, wqT, HIDN, HIDN);
  transpose_f2b<<<tHH, 256, 0, stream>>>(wk, wkT, HIDN, HIDN);
  transpose_f2b<<<tHH, 256, 0, stream>>>(wv, wvT, HIDN, HIDN);
  transpose_f2b<<<tHH, 256, 0, stream>>>(wo, woT, HIDN, HIDN);
  transpose_f2b<<<dim3(INTERN / 32, HIDN / 32), 256, 0, stream>>>(wg, wgT, HIDN, INTERN);
  transpose_f2b<<<dim3(INTERN / 32, HIDN / 32), 256, 0, stream>>>(wu, wuT, HIDN, INTERN);
  transpose_f2b<<<dim3(HIDN / 32, INTERN / 32), 256, 0, stream>>>(wd, wdT, INTERN, HIDN);

  dim3 gHH(HIDN / 128, SEQ / 128);
  gemm_bt<0><<<gHH, 256, 0, stream>>>(xn, wqT, SEQ, HIDN, HIDN, nullptr, qb, nullptr, nullptr);
  gemm_bt<0><<<gHH, 256, 0, stream>>>(xn, wkT, SEQ, HIDN, HIDN, nullptr, kb, nullptr, nullptr);
  gemm_bt<0><<<gHH, 256, 0, stream>>>(xn, wvT, SEQ, HIDN, HIDN, nullptr, vb, nullptr, nullptr);
  rope_kernel<<<SEQ, 256, 0, stream>>>(qb, fcos, fsin);
  rope_kernel<<<SEQ, 256, 0, stream>>>(kb, fcos, fsin);
  transpose_b2b<<<dim3(HIDN / 32, SEQ / 32), 256, 0, stream>>>(vb, vt, SEQ, HIDN);
  attn_kernel<<<dim3(SEQ / 128, NHEAD), 256, 0, stream>>>(qb, kb, vt, vb);
  gemm_bt<1><<<gHH, 256, 0, stream>>>(vb, woT, SEQ, HIDN, HIDN, hbuf, nullptr, x, nullptr);
  rmsnorm_kernel<<<SEQ, 256, 0, stream>>>(hbuf, n2, xn);
  dim3 gHI(INTERN / 128, SEQ / 128);
  gemm_bt<0><<<gHI, 256, 0, stream>>>(xn, wgT, SEQ, INTERN, HIDN, nullptr, gbuf, nullptr, nullptr);
  gemm_bt<2><<<gHI, 256, 0, stream>>>(xn, wuT, SEQ, INTERN, HIDN, nullptr, ffnb, nullptr, gbuf);
  gemm_bt<1><<<gHH, 256, 0, stream>>>(ffnb, wdT, SEQ, HIDN, INTERN, out, nullptr, hbuf, nullptr);
}

// Round 5
// 1025.906 us; speedup vs baseline: 1.2570x; 1.0741x over previous
//
#include <hip/hip_runtime.h>
#include <hip/hip_bf16.h>
#include <cstdint>
#include <cstddef>

#define HIDN 2048
#define NHEAD 16
#define HDIM 128
#define INTERN 5632
#define SEQ 4096

typedef __bf16 bf16x8 __attribute__((ext_vector_type(8)));
typedef float f32x4 __attribute__((ext_vector_type(4)));
typedef float f32x16 __attribute__((ext_vector_type(16)));
typedef unsigned short u16x8 __attribute__((ext_vector_type(8)));

__device__ __forceinline__ float bf2f(unsigned short u) {
  unsigned v = ((unsigned)u) << 16; float f; __builtin_memcpy(&f, &v, 4); return f;
}
__device__ __forceinline__ unsigned short f2bf(float f) {
  unsigned u; __builtin_memcpy(&u, &f, 4);
  unsigned r = 0x7FFFu + ((u >> 16) & 1u);
  return (unsigned short)((u + r) >> 16);
}
// async global->LDS, 16B per lane. dst must be wave-linear: base + lane*16B.
__device__ __forceinline__ void gl_lds16(const unsigned short* g, unsigned short* l) {
  __builtin_amdgcn_global_load_lds((unsigned int __attribute__((address_space(1)))*)g,
                                   (unsigned int __attribute__((address_space(3)))*)l,
                                   16, 0, 0);
}
// pack two f32 -> one u32 of 2x bf16 (lo in low half)
__device__ __forceinline__ unsigned cvtpk(float lo, float hi) {
  unsigned r; asm("v_cvt_pk_bf16_f32 %0, %1, %2" : "=v"(r) : "v"(lo), "v"(hi)); return r;
}
// swap a.hi-lanes <-> b.lo-lanes: a' = {a.lo, b.lo}, b' = {a.hi, b.hi}
__device__ __forceinline__ void plswap(unsigned& a, unsigned& b) {
  asm("v_permlane32_swap_b32 %0, %1" : "+v"(a), "+v"(b));
}
__device__ __forceinline__ bf16x8 mk_pa(unsigned w0, unsigned w1, unsigned w2, unsigned w3) {
  union { unsigned u[4]; bf16x8 v; } t; t.u[0] = w0; t.u[1] = w1; t.u[2] = w2; t.u[3] = w3; return t.v;
}

// ---------------- RMSNorm: fp32 row -> bf16 row ----------------
__global__ __launch_bounds__(256) void rmsnorm_kernel(const float* __restrict__ x,
                                                      const float* __restrict__ wgt,
                                                      unsigned short* __restrict__ out) {
  const int tid = threadIdx.x;
  const size_t base = (size_t)blockIdx.x * HIDN + tid * 8;
  f32x4 a = *(const f32x4*)(x + base);
  f32x4 b = *(const f32x4*)(x + base + 4);
  float ss = a[0]*a[0]+a[1]*a[1]+a[2]*a[2]+a[3]*a[3]
           + b[0]*b[0]+b[1]*b[1]+b[2]*b[2]+b[3]*b[3];
#pragma unroll
  for (int off = 32; off >= 1; off >>= 1) ss += __shfl_xor(ss, off, 64);
  __shared__ float red[4];
  if ((tid & 63) == 0) red[tid >> 6] = ss;
  __syncthreads();
  float tot = red[0] + red[1] + red[2] + red[3];
  float sc = 1.f / sqrtf(tot * (1.f / HIDN) + 1e-6f);
  f32x4 w0 = *(const f32x4*)(wgt + tid * 8);
  f32x4 w1 = *(const f32x4*)(wgt + tid * 8 + 4);
  u16x8 o;
#pragma unroll
  for (int i = 0; i < 4; ++i) { o[i] = f2bf(a[i] * sc * w0[i]); o[i+4] = f2bf(b[i] * sc * w1[i]); }
  *(u16x8*)(out + base) = o;
}

// ---------------- transpose fp32 [R][C] -> bf16 [C][R] ----------------
__global__ __launch_bounds__(256) void transpose_f2b(const float* __restrict__ in,
                                                     unsigned short* __restrict__ out,
                                                     int R, int C) {
  __shared__ float tile[32][33];
  const int bx = blockIdx.x * 32, by = blockIdx.y * 32;
  const int tx = threadIdx.x & 31, ty = threadIdx.x >> 5;
#pragma unroll
  for (int i = 0; i < 32; i += 8)
    tile[ty + i][tx] = in[(size_t)(by + ty + i) * C + bx + tx];
  __syncthreads();
#pragma unroll
  for (int i = 0; i < 32; i += 8)
    out[(size_t)(bx + ty + i) * R + by + tx] = f2bf(tile[tx][ty + i]);
}

// ---------------- transpose bf16 [R][C] -> bf16 [C][R] ----------------
__global__ __launch_bounds__(256) void transpose_b2b(const unsigned short* __restrict__ in,
                                                     unsigned short* __restrict__ out,
                                                     int R, int C) {
  __shared__ unsigned short tile[32][33];
  const int bx = blockIdx.x * 32, by = blockIdx.y * 32;
  const int tx = threadIdx.x & 31, ty = threadIdx.x >> 5;
#pragma unroll
  for (int i = 0; i < 32; i += 8)
    tile[ty + i][tx] = in[(size_t)(by + ty + i) * C + bx + tx];
  __syncthreads();
#pragma unroll
  for (int i = 0; i < 32; i += 8)
    out[(size_t)(bx + ty + i) * R + by + tx] = tile[tx][ty + i];
}

// ---------------- RoPE in-place on bf16 [SEQ][HIDN] ----------------
__global__ __launch_bounds__(256) void rope_kernel(unsigned short* __restrict__ v,
                                                   const float* __restrict__ cosb,
                                                   const float* __restrict__ sinb) {
  const int s = blockIdx.x, tid = threadIdx.x;
  const size_t base = (size_t)s * HIDN + tid * 8;
  u16x8 u = *(const u16x8*)(v + base);
  const int j0 = ((tid * 8) & 127) >> 1;
  const float* cr = cosb + s * 64 + j0;
  const float* sr = sinb + s * 64 + j0;
  u16x8 o;
#pragma unroll
  for (int p = 0; p < 4; ++p) {
    float re = bf2f(u[2*p]), im = bf2f(u[2*p+1]);
    float c = cr[p], sn = sr[p];
    o[2*p]   = f2bf(re * c - im * sn);
    o[2*p+1] = f2bf(re * sn + im * c);
  }
  *(u16x8*)(v + base) = o;
}

// ---------------- bf16 GEMM, m97 structure + T1 XCD swizzle ----------------
template<int EPI>
__global__ __launch_bounds__(256) void gemm_bt(const unsigned short* __restrict__ A,
                                               const unsigned short* __restrict__ Bt,
                                               int M, int N, int K,
                                               float* __restrict__ outF,
                                               unsigned short* __restrict__ outB,
                                               const float* __restrict__ res,
                                               const unsigned short* __restrict__ gate) {
  __shared__ unsigned short As[128 * 32];
  __shared__ unsigned short Bs[128 * 32];
  const int tid = threadIdx.x;
  const int w = tid >> 6, l = tid & 63;
  const int lr = l & 15, lk = (l >> 4) * 8;
  // T1: XCD-aware bijective swizzle (all grids here have nwg % 8 == 0)
  const int nwg = gridDim.x * gridDim.y;
  const int orig = blockIdx.y * gridDim.x + blockIdx.x;
  const int cpx = nwg >> 3;
  const int swz = (orig & 7) * cpx + (orig >> 3);
  const int m0 = (swz / gridDim.x) * 128, n0 = (swz % gridDim.x) * 128;
  const int wm = (w >> 1) * 64, wn = (w & 1) * 64;

  f32x4 acc[4][4];
#pragma unroll
  for (int i = 0; i < 4; ++i)
#pragma unroll
    for (int j = 0; j < 4; ++j) acc[i][j] = (f32x4){0.f, 0.f, 0.f, 0.f};

  const int srow = tid >> 2, scol = (tid & 3) * 8;
  const unsigned short* a0 = A + (size_t)(m0 + srow) * K + scol;
  const unsigned short* a1 = A + (size_t)(m0 + 64 + srow) * K + scol;
  const unsigned short* b0 = Bt + (size_t)(n0 + srow) * K + scol;
  const unsigned short* b1 = Bt + (size_t)(n0 + 64 + srow) * K + scol;
  unsigned short* ad0 = As + tid * 8;
  unsigned short* ad1 = As + 2048 + tid * 8;
  unsigned short* bd0 = Bs + tid * 8;
  unsigned short* bd1 = Bs + 2048 + tid * 8;

  for (int k0 = 0; k0 < K; k0 += 32) {
    gl_lds16(a0 + k0, ad0);
    gl_lds16(a1 + k0, ad1);
    gl_lds16(b0 + k0, bd0);
    gl_lds16(b1 + k0, bd1);
    __syncthreads();
    bf16x8 af[4], bfr[4];
#pragma unroll
    for (int m = 0; m < 4; ++m) af[m] = *(const bf16x8*)&As[(wm + m * 16 + lr) * 32 + lk];
#pragma unroll
    for (int n = 0; n < 4; ++n) bfr[n] = *(const bf16x8*)&Bs[(wn + n * 16 + lr) * 32 + lk];
#pragma unroll
    for (int m = 0; m < 4; ++m)
#pragma unroll
      for (int n = 0; n < 4; ++n)
        acc[m][n] = __builtin_amdgcn_mfma_f32_16x16x32_bf16(af[m], bfr[n], acc[m][n], 0, 0, 0);
    __syncthreads();
  }

#pragma unroll
  for (int m = 0; m < 4; ++m)
#pragma unroll
    for (int n = 0; n < 4; ++n)
#pragma unroll
      for (int r = 0; r < 4; ++r) {
        const int row = m0 + wm + m * 16 + (l >> 4) * 4 + r;
        const int col = n0 + wn + n * 16 + lr;
        const size_t idx = (size_t)row * N + col;
        float v = acc[m][n][r];
        if (EPI == 0) {
          outB[idx] = f2bf(v);
        } else if (EPI == 1) {
          outF[idx] = res[idx] + v;
        } else {
          float g = bf2f(gate[idx]);
          float s = g / (1.f + __expf(-g));
          outB[idx] = f2bf(s * v);
        }
      }
}

// ---------------- causal flash attention v3: swapped QK^T, in-register softmax ----------------
// 4 warps x 32 q-rows (QBLK=128), KVBLK=64, dbuf K/V in LDS, no P round-trip.
// Grid: 512 blocks 1D. Complementary heavy/light pairing so co-resident block
// pairs (within-XCD sequence k and k+32) sum to uniform 66 tile-units.
__global__ __launch_bounds__(256) void attn_kernel(const unsigned short* __restrict__ Q,
                                                   const unsigned short* __restrict__ Kb,
                                                   const unsigned short* __restrict__ Vt,
                                                   unsigned short* __restrict__ Ob) {
  __shared__ unsigned short Ks[2][64 * 128];   // [kv][d], 256B rows, (row&15)<<4 swizzle
  __shared__ unsigned short Vs[2][128 * 64];   // [d][kv], 128B rows, (row&7)<<4 swizzle
  __shared__ float alS[4][32];                 // per-warp q-indexed gather scratch
  const int tid = threadIdx.x, w = tid >> 6, l = tid & 63;
  const int lq = l & 31, hi = l >> 5;
  // work mapping: XCD c = bid&7 gets heads 2c, 2c+1; k<32 heavy (j=31..16), k>=32 light (j=0..15)
  const int bid = blockIdx.x;
  const int c = bid & 7, k = bid >> 3;
  const int kk = (k < 32) ? k : (k - 32);
  const int h = 2 * c + (kk >> 4);
  const int j = (k < 32) ? (31 - (kk & 15)) : (kk & 15);
  const int qb0 = j * 128;
  const int qw0 = qb0 + w * 32;

  // Q as B-operand: lane holds q-col = lq, d = c*16 + hi*8 .. +7
  bf16x8 qf[8];
#pragma unroll
  for (int cq = 0; cq < 8; ++cq)
    qf[cq] = *(const bf16x8*)(Q + (size_t)(qw0 + lq) * HIDN + h * HDIM + cq * 16 + hi * 8);

  float m2 = -1e30f, lsum = 0.f;   // per-lane: running max / denom for q = lq (log2 domain)
  f32x16 o[4];
#pragma unroll
  for (int dc = 0; dc < 4; ++dc) o[dc] = (f32x16){};

  const int krow = tid >> 4, kc2 = (tid & 15) * 16;   // K stage: 256B rows, byte col
  const int vrow = tid >> 3, vc2 = (tid & 7) * 16;    // V stage: 128B rows, byte col
  const int nt = qb0 / 64 + 2;

#define STAGE(T, B)                                                                          \
  {                                                                                          \
    const int kv0_ = (T) * 64;                                                               \
    _Pragma("unroll")                                                                        \
    for (int i = 0; i < 4; ++i) {                                                            \
      const int row = i * 16 + krow;                                                         \
      gl_lds16(Kb + (size_t)(kv0_ + row) * HIDN + h * HDIM + ((kc2 ^ ((row & 15) << 4)) >> 1), \
               &Ks[B][i * 2048 + tid * 8]);                                                  \
    }                                                                                        \
    _Pragma("unroll")                                                                        \
    for (int i = 0; i < 4; ++i) {                                                            \
      const int row = i * 32 + vrow;                                                         \
      gl_lds16(Vt + (size_t)(h * HDIM + row) * SEQ + kv0_ + ((vc2 ^ ((row & 7) << 4)) >> 1),   \
               &Vs[B][i * 2048 + tid * 8]);                                                  \
    }                                                                                        \
  }
#define LDK(row_, c_) (*(const bf16x8*)&Ks[cur][(row_) * 128 + ((((c_) * 32 + hi * 16) ^ (((row_) & 15) << 4)) >> 1)])
#define LDV(row_, ks_) (*(const bf16x8*)&Vs[cur][(row_) * 64 + ((((ks_) * 32 + hi * 16) ^ (((row_) & 7) << 4)) >> 1)])

  STAGE(0, 0);
  __syncthreads();

  for (int t = 0; t < nt; ++t) {
    const int cur = t & 1, kv0 = t * 64;
    if (t + 1 < nt) STAGE(t + 1, cur ^ 1);   // prefetch overlaps compute

    if (kv0 <= qw0 + 31) {   // warp-uniform: skip fully-masked tiles
      // ---- QK^T (swapped): s0 = kv 0..31, s1 = kv 32..63 of this tile ----
      f32x16 s0 = {}, s1 = {};
      __builtin_amdgcn_s_setprio(1);
#pragma unroll
      for (int cq = 0; cq < 8; ++cq) {
        s0 = __builtin_amdgcn_mfma_f32_32x32x16_bf16(LDK(lq, cq), qf[cq], s0, 0, 0, 0);
        s1 = __builtin_amdgcn_mfma_f32_32x32x16_bf16(LDK(32 + lq, cq), qf[cq], s1, 0, 0, 0);
      }
      __builtin_amdgcn_s_setprio(0);
      // ---- scale into exp2 domain; causal mask on diagonal-overlap tiles ----
      const float SC2 = 0.08838834764831845f * 1.44269504088896f;
#pragma unroll
      for (int r = 0; r < 16; ++r) { s0[r] *= SC2; s1[r] *= SC2; }
      if (kv0 + 63 > qw0) {
        const int qi = qw0 + lq;
#pragma unroll
        for (int r = 0; r < 16; ++r) {
          const int kvr = kv0 + (r & 3) + 8 * (r >> 2) + 4 * hi;
          if (kvr > qi) s0[r] = -1e30f;
          if (kvr + 32 > qi) s1[r] = -1e30f;
        }
      }
      // ---- row max: 31 in-reg + 1 cross-half exchange ----
      float vm = s0[0];
#pragma unroll
      for (int r = 1; r < 16; ++r) vm = fmaxf(vm, s0[r]);
#pragma unroll
      for (int r = 0; r < 16; ++r) vm = fmaxf(vm, s1[r]);
      vm = fmaxf(vm, __shfl_xor(vm, 32, 64));
      // ---- T13 defer-max: rescale only when max grows > 8 nats (11.54 bits) ----
      float al = 1.f;
      if (!__all(vm <= m2 + 11.54f)) {
        const float mn = fmaxf(m2, vm);
        al = exp2f(m2 - mn);
        m2 = mn;
        if (l < 32) alS[w][l] = al;
#pragma unroll
        for (int r = 0; r < 16; ++r) {
          const float a = alS[w][(r & 3) + 8 * (r >> 2) + 4 * hi];
          o[0][r] *= a; o[1][r] *= a; o[2][r] *= a; o[3][r] *= a;
        }
      }
      // ---- P = exp2(s - m); row sum; pack to PV A-fragments in-register (T12) ----
      float p[32];
#pragma unroll
      for (int r = 0; r < 16; ++r) { p[r] = exp2f(s0[r] - m2); p[16 + r] = exp2f(s1[r] - m2); }
      float rsum = 0.f;
#pragma unroll
      for (int r = 0; r < 32; ++r) rsum += p[r];
      lsum = lsum * al + (rsum + __shfl_xor(rsum, 32, 64));
      bf16x8 pa[4];
#pragma unroll
      for (int hh = 0; hh < 2; ++hh) {
        unsigned ua[8];
#pragma unroll
        for (int i = 0; i < 8; ++i) ua[i] = cvtpk(p[hh * 16 + 2 * i], p[hh * 16 + 2 * i + 1]);
        plswap(ua[0], ua[2]); plswap(ua[1], ua[3]);
        plswap(ua[4], ua[6]); plswap(ua[5], ua[7]);
        pa[hh * 2]     = mk_pa(ua[0], ua[1], ua[2], ua[3]);
        pa[hh * 2 + 1] = mk_pa(ua[4], ua[5], ua[6], ua[7]);
      }
      // ---- PV: O[q][d] += P[q][kv] * V[kv][d] ----
      __builtin_amdgcn_s_setprio(1);
#pragma unroll
      for (int dc = 0; dc < 4; ++dc) {
        const int vr = dc * 32 + lq;
#pragma unroll
        for (int ks = 0; ks < 4; ++ks)
          o[dc] = __builtin_amdgcn_mfma_f32_32x32x16_bf16(pa[ks], LDV(vr, ks), o[dc], 0, 0, 0);
      }
      __builtin_amdgcn_s_setprio(0);
    }
    __syncthreads();
  }
#undef STAGE
#undef LDK
#undef LDV

  // ---- normalize (1/lsum gather) + store ----
  if (l < 32) alS[w][l] = 1.f / lsum;
#pragma unroll
  for (int r = 0; r < 16; ++r) {
    const int q = (r & 3) + 8 * (r >> 2) + 4 * hi;
    const float rr = alS[w][q];
    const size_t rowb = (size_t)(qw0 + q) * HIDN + h * HDIM + lq;
    Ob[rowb]      = f2bf(o[0][r] * rr);
    Ob[rowb + 32] = f2bf(o[1][r] * rr);
    Ob[rowb + 64] = f2bf(o[2][r] * rr);
    Ob[rowb + 96] = f2bf(o[3][r] * rr);
  }
}

extern "C" void kernel_launch(void* const* d_in, const int* in_sizes, int n_in,
                              void* d_out, int out_size, void* d_ws, size_t ws_size,
                              hipStream_t stream) {
  const float* x    = (const float*)d_in[0];
  const float* fcos = (const float*)d_in[1];
  const float* fsin = (const float*)d_in[2];
  // d_in[3] = mask: causal computed directly
  const float* wq = (const float*)d_in[4];
  const float* wk = (const float*)d_in[5];
  const float* wv = (const float*)d_in[6];
  const float* wo = (const float*)d_in[7];
  const float* wg = (const float*)d_in[8];
  const float* wu = (const float*)d_in[9];
  const float* wd = (const float*)d_in[10];
  const float* n1 = (const float*)d_in[11];
  const float* n2 = (const float*)d_in[12];
  float* out = (float*)d_out;

  const size_t HH = (size_t)HIDN * HIDN, HI = (size_t)HIDN * INTERN;
  const size_t SH = (size_t)SEQ * HIDN, SI = (size_t)SEQ * INTERN;
  unsigned short* p = (unsigned short*)d_ws;
  unsigned short* wqT = p; p += HH;
  unsigned short* wkT = p; p += HH;
  unsigned short* wvT = p; p += HH;
  unsigned short* woT = p; p += HH;
  unsigned short* wgT = p; p += HI;
  unsigned short* wuT = p; p += HI;
  unsigned short* wdT = p; p += HI;
  unsigned short* xn  = p; p += SH;   // xn, later hn
  unsigned short* qb  = p; p += SH;
  unsigned short* kb  = p; p += SH;
  unsigned short* vb  = p; p += SH;   // v, later attention out
  unsigned short* vt  = p; p += SH;
  unsigned short* ffnb = p; p += SI;
  float* hbuf = (float*)p;            // SH floats
  unsigned short* gbuf = qb;          // gate reuses dead q/k/(part of v) region

  rmsnorm_kernel<<<SEQ, 256, 0, stream>>>(x, n1, xn);
  dim3 tHH(HIDN / 32, HIDN / 32);
  transpose_f2b<<<tHH, 256, 0, stream>>>(wq, wqT, HIDN, HIDN);
  transpose_f2b<<<tHH, 256, 0, stream>>>(wk, wkT, HIDN, HIDN);
  transpose_f2b<<<tHH, 256, 0, stream>>>(wv, wvT, HIDN, HIDN);
  transpose_f2b<<<tHH, 256, 0, stream>>>(wo, woT, HIDN, HIDN);
  transpose_f2b<<<dim3(INTERN / 32, HIDN / 32), 256, 0, stream>>>(wg, wgT, HIDN, INTERN);
  transpose_f2b<<<dim3(INTERN / 32, HIDN / 32), 256, 0, stream>>>(wu, wuT, HIDN, INTERN);
  transpose_f2b<<<dim3(HIDN / 32, INTERN / 32), 256, 0, stream>>>(wd, wdT, INTERN, HIDN);

  dim3 gHH(HIDN / 128, SEQ / 128);
  gemm_bt<0><<<gHH, 256, 0, stream>>>(xn, wqT, SEQ, HIDN, HIDN, nullptr, qb, nullptr, nullptr);
  gemm_bt<0><<<gHH, 256, 0, stream>>>(xn, wkT, SEQ, HIDN, HIDN, nullptr, kb, nullptr, nullptr);
  gemm_bt<0><<<gHH, 256, 0, stream>>>(xn, wvT, SEQ, HIDN, HIDN, nullptr, vb, nullptr, nullptr);
  rope_kernel<<<SEQ, 256, 0, stream>>>(qb, fcos, fsin);
  rope_kernel<<<SEQ, 256, 0, stream>>>(kb, fcos, fsin);
  transpose_b2b<<<dim3(HIDN / 32, SEQ / 32), 256, 0, stream>>>(vb, vt, SEQ, HIDN);
  attn_kernel<<<dim3(SEQ / 128 * NHEAD), 256, 0, stream>>>(qb, kb, vt, vb);
  gemm_bt<1><<<gHH, 256, 0, stream>>>(vb, woT, SEQ, HIDN, HIDN, hbuf, nullptr, x, nullptr);
  rmsnorm_kernel<<<SEQ, 256, 0, stream>>>(hbuf, n2, xn);
  dim3 gHI(INTERN / 128, SEQ / 128);
  gemm_bt<0><<<gHI, 256, 0, stream>>>(xn, wgT, SEQ, INTERN, HIDN, nullptr, gbuf, nullptr, nullptr);
  gemm_bt<2><<<gHI, 256, 0, stream>>>(xn, wuT, SEQ, INTERN, HIDN, nullptr, ffnb, nullptr, gbuf);
  gemm_bt<1><<<gHH, 256, 0, stream>>>(ffnb, wdT, SEQ, HIDN, INTERN, out, nullptr, hbuf, nullptr);
}

// Round 6
// 905.971 us; speedup vs baseline: 1.4234x; 1.1324x over previous
//
#include <hip/hip_runtime.h>
#include <hip/hip_bf16.h>
#include <cstdint>
#include <cstddef>

#define HIDN 2048
#define NHEAD 16
#define HDIM 128
#define INTERN 5632
#define SEQ 4096

typedef __bf16 bf16x8 __attribute__((ext_vector_type(8)));
typedef float f32x4 __attribute__((ext_vector_type(4)));
typedef float f32x16 __attribute__((ext_vector_type(16)));
typedef unsigned short u16x8 __attribute__((ext_vector_type(8)));

__device__ __forceinline__ float bf2f(unsigned short u) {
  unsigned v = ((unsigned)u) << 16; float f; __builtin_memcpy(&f, &v, 4); return f;
}
__device__ __forceinline__ unsigned short f2bf(float f) {
  unsigned u; __builtin_memcpy(&u, &f, 4);
  unsigned r = 0x7FFFu + ((u >> 16) & 1u);
  return (unsigned short)((u + r) >> 16);
}
// async global->LDS, 16B per lane. dst must be wave-linear: base + lane*16B.
__device__ __forceinline__ void gl_lds16(const unsigned short* g, unsigned short* l) {
  __builtin_amdgcn_global_load_lds((unsigned int __attribute__((address_space(1)))*)g,
                                   (unsigned int __attribute__((address_space(3)))*)l,
                                   16, 0, 0);
}
// pack two f32 -> one u32 of 2x bf16 (lo in low half)
__device__ __forceinline__ unsigned cvtpk(float lo, float hi) {
  unsigned r; asm("v_cvt_pk_bf16_f32 %0, %1, %2" : "=v"(r) : "v"(lo), "v"(hi)); return r;
}
// swap a.hi-lanes <-> b.lo-lanes: a' = {a.lo, b.lo}, b' = {a.hi, b.hi}
__device__ __forceinline__ void plswap(unsigned& a, unsigned& b) {
  asm("v_permlane32_swap_b32 %0, %1" : "+v"(a), "+v"(b));
}
__device__ __forceinline__ bf16x8 mk_pa(unsigned w0, unsigned w1, unsigned w2, unsigned w3) {
  union { unsigned u[4]; bf16x8 v; } t; t.u[0] = w0; t.u[1] = w1; t.u[2] = w2; t.u[3] = w3; return t.v;
}

// ---------------- RMSNorm: fp32 row -> bf16 row ----------------
__global__ __launch_bounds__(256) void rmsnorm_kernel(const float* __restrict__ x,
                                                      const float* __restrict__ wgt,
                                                      unsigned short* __restrict__ out) {
  const int tid = threadIdx.x;
  const size_t base = (size_t)blockIdx.x * HIDN + tid * 8;
  f32x4 a = *(const f32x4*)(x + base);
  f32x4 b = *(const f32x4*)(x + base + 4);
  float ss = a[0]*a[0]+a[1]*a[1]+a[2]*a[2]+a[3]*a[3]
           + b[0]*b[0]+b[1]*b[1]+b[2]*b[2]+b[3]*b[3];
#pragma unroll
  for (int off = 32; off >= 1; off >>= 1) ss += __shfl_xor(ss, off, 64);
  __shared__ float red[4];
  if ((tid & 63) == 0) red[tid >> 6] = ss;
  __syncthreads();
  float tot = red[0] + red[1] + red[2] + red[3];
  float sc = 1.f / sqrtf(tot * (1.f / HIDN) + 1e-6f);
  f32x4 w0 = *(const f32x4*)(wgt + tid * 8);
  f32x4 w1 = *(const f32x4*)(wgt + tid * 8 + 4);
  u16x8 o;
#pragma unroll
  for (int i = 0; i < 4; ++i) { o[i] = f2bf(a[i] * sc * w0[i]); o[i+4] = f2bf(b[i] * sc * w1[i]); }
  *(u16x8*)(out + base) = o;
}

// ---------------- transpose fp32 [R][C] -> bf16 [C][R] ----------------
__global__ __launch_bounds__(256) void transpose_f2b(const float* __restrict__ in,
                                                     unsigned short* __restrict__ out,
                                                     int R, int C) {
  __shared__ float tile[32][33];
  const int bx = blockIdx.x * 32, by = blockIdx.y * 32;
  const int tx = threadIdx.x & 31, ty = threadIdx.x >> 5;
#pragma unroll
  for (int i = 0; i < 32; i += 8)
    tile[ty + i][tx] = in[(size_t)(by + ty + i) * C + bx + tx];
  __syncthreads();
#pragma unroll
  for (int i = 0; i < 32; i += 8)
    out[(size_t)(bx + ty + i) * R + by + tx] = f2bf(tile[tx][ty + i]);
}

// ---------------- transpose bf16 [R][C] -> bf16 [C][R] ----------------
__global__ __launch_bounds__(256) void transpose_b2b(const unsigned short* __restrict__ in,
                                                     unsigned short* __restrict__ out,
                                                     int R, int C) {
  __shared__ unsigned short tile[32][33];
  const int bx = blockIdx.x * 32, by = blockIdx.y * 32;
  const int tx = threadIdx.x & 31, ty = threadIdx.x >> 5;
#pragma unroll
  for (int i = 0; i < 32; i += 8)
    tile[ty + i][tx] = in[(size_t)(by + ty + i) * C + bx + tx];
  __syncthreads();
#pragma unroll
  for (int i = 0; i < 32; i += 8)
    out[(size_t)(bx + ty + i) * R + by + tx] = tile[tx][ty + i];
}

// ---------------- RoPE in-place on bf16 [SEQ][HIDN] ----------------
__global__ __launch_bounds__(256) void rope_kernel(unsigned short* __restrict__ v,
                                                   const float* __restrict__ cosb,
                                                   const float* __restrict__ sinb) {
  const int s = blockIdx.x, tid = threadIdx.x;
  const size_t base = (size_t)s * HIDN + tid * 8;
  u16x8 u = *(const u16x8*)(v + base);
  const int j0 = ((tid * 8) & 127) >> 1;
  const float* cr = cosb + s * 64 + j0;
  const float* sr = sinb + s * 64 + j0;
  u16x8 o;
#pragma unroll
  for (int p = 0; p < 4; ++p) {
    float re = bf2f(u[2*p]), im = bf2f(u[2*p+1]);
    float c = cr[p], sn = sr[p];
    o[2*p]   = f2bf(re * c - im * sn);
    o[2*p+1] = f2bf(re * sn + im * c);
  }
  *(u16x8*)(v + base) = o;
}

// ---------------- bf16 GEMM v2: BM=128 x BN=256, BK=64, 8 waves, counted-vmcnt pipeline ----
// C[M,N] = A[M,K] * Bt[N,K]^T. 1D grid (nwg = (M/128)*(N/256)), XCD-swizzled.
// EPI 0: outB=bf16(acc) [stride N]; 1: outF=res+acc [fp32]; 2: outB=bf16(silu(gate)*acc);
// EPI 3: qkv split-store (N=6144 -> qb/kb/vb, stride 2048).
template<int EPI>
__global__ __launch_bounds__(512) void gemm2(const unsigned short* __restrict__ Ag,
                                             const unsigned short* __restrict__ Btg,
                                             int M, int N, int K, int nbx,
                                             float* __restrict__ outF,
                                             unsigned short* __restrict__ outB,
                                             const float* __restrict__ res,
                                             const unsigned short* __restrict__ gate,
                                             unsigned short* __restrict__ qb_,
                                             unsigned short* __restrict__ kb_,
                                             unsigned short* __restrict__ vb_) {
  __shared__ unsigned short As[2][128 * 64];   // 128B rows, (row&7)<<4 byte-XOR swizzle
  __shared__ unsigned short Bs[2][256 * 64];
  const int tid = threadIdx.x;
  const int wid = tid >> 6, l = tid & 63;
  const int wr = wid >> 2, wc = wid & 3;        // 2 x 4 wave grid, wave tile 64x64
  const int lr = l & 15;
  const int lkb = ((l >> 4) & 3) << 4;          // byte col of lane's 16B within 64B k-step
  const int arsw = (lr & 7) << 4;               // read-side swizzle (row&7 == lr&7)
  // XCD-aware bijective swizzle (all grids have nwg % 8 == 0)
  const int nwg = gridDim.x;
  const int orig = blockIdx.x;
  const int swz = (orig & 7) * (nwg >> 3) + (orig >> 3);
  const int m0 = (swz / nbx) * 128, n0 = (swz % nbx) * 256;
  // staging geometry: per K-tile A=2 loads, B=4 loads per thread (6 total)
  const int arow = tid >> 3;                    // 0..63
  const int scol = (((tid & 7) << 4) ^ ((arow & 7) << 4)) >> 1;   // pre-swizzled src elem col

#define GSTAGE(T, B)                                                        \
  {                                                                         \
    const int k0_ = (T) << 6;                                               \
    _Pragma("unroll")                                                       \
    for (int i = 0; i < 2; ++i)                                             \
      gl_lds16(Ag + (size_t)(m0 + i * 64 + arow) * K + k0_ + scol,          \
               &As[B][(i * 512 + tid) * 8]);                                \
    _Pragma("unroll")                                                       \
    for (int i = 0; i < 4; ++i)                                             \
      gl_lds16(Btg + (size_t)(n0 + i * 64 + arow) * K + k0_ + scol,         \
               &Bs[B][(i * 512 + tid) * 8]);                                \
  }
#define LDA(B, mf, ks) (*(const bf16x8*)&As[B][(wr * 64 + (mf) * 16 + lr) * 64 + (((((ks) << 6) | lkb) ^ arsw) >> 1)])
#define LDB(B, nf, ks) (*(const bf16x8*)&Bs[B][(wc * 64 + (nf) * 16 + lr) * 64 + (((((ks) << 6) | lkb) ^ arsw) >> 1)])

  f32x4 acc[4][4];
#pragma unroll
  for (int i = 0; i < 4; ++i)
#pragma unroll
    for (int j = 0; j < 4; ++j) acc[i][j] = (f32x4){0.f, 0.f, 0.f, 0.f};

  GSTAGE(0, 0);
  GSTAGE(1, 1);
  asm volatile("s_waitcnt vmcnt(6)" ::: "memory");   // tile 0 landed (tile 1 in flight)
  __builtin_amdgcn_sched_barrier(0);
  __builtin_amdgcn_s_barrier();

  const int NT = K >> 6;
  for (int t = 0; t < NT; ++t) {
    const int cur = t & 1;
    bf16x8 a0[4], b0[4], a1[4], b1[4];
#pragma unroll
    for (int mf = 0; mf < 4; ++mf) a0[mf] = LDA(cur, mf, 0);
#pragma unroll
    for (int nf = 0; nf < 4; ++nf) b0[nf] = LDB(cur, nf, 0);
#pragma unroll
    for (int mf = 0; mf < 4; ++mf) a1[mf] = LDA(cur, mf, 1);
#pragma unroll
    for (int nf = 0; nf < 4; ++nf) b1[nf] = LDB(cur, nf, 1);
    // k-step 0 MFMAs overlap the ks1 LDS reads
    __builtin_amdgcn_s_setprio(1);
#pragma unroll
    for (int mf = 0; mf < 4; ++mf)
#pragma unroll
      for (int nf = 0; nf < 4; ++nf)
        acc[mf][nf] = __builtin_amdgcn_mfma_f32_16x16x32_bf16(a0[mf], b0[nf], acc[mf][nf], 0, 0, 0);
    __builtin_amdgcn_s_setprio(0);
    // all waves done reading buf[cur] -> safe to overwrite
    asm volatile("s_waitcnt lgkmcnt(0)" ::: "memory");
    __builtin_amdgcn_sched_barrier(0);
    __builtin_amdgcn_s_barrier();
    if (t + 2 < NT) GSTAGE(t + 2, cur);
    __builtin_amdgcn_s_setprio(1);
#pragma unroll
    for (int mf = 0; mf < 4; ++mf)
#pragma unroll
      for (int nf = 0; nf < 4; ++nf)
        acc[mf][nf] = __builtin_amdgcn_mfma_f32_16x16x32_bf16(a1[mf], b1[nf], acc[mf][nf], 0, 0, 0);
    __builtin_amdgcn_s_setprio(0);
    if (t + 2 < NT) { asm volatile("s_waitcnt vmcnt(6)" ::: "memory"); }   // t+1 landed
    else            { asm volatile("s_waitcnt vmcnt(0)" ::: "memory"); }   // drain tail
    __builtin_amdgcn_sched_barrier(0);
    __builtin_amdgcn_s_barrier();
  }
#undef GSTAGE
#undef LDA
#undef LDB

#pragma unroll
  for (int mf = 0; mf < 4; ++mf)
#pragma unroll
    for (int nf = 0; nf < 4; ++nf)
#pragma unroll
      for (int r = 0; r < 4; ++r) {
        const int row = m0 + wr * 64 + mf * 16 + (l >> 4) * 4 + r;
        const int col = n0 + wc * 64 + nf * 16 + lr;
        float v = acc[mf][nf][r];
        if (EPI == 0) {
          outB[(size_t)row * N + col] = f2bf(v);
        } else if (EPI == 1) {
          const size_t idx = (size_t)row * N + col;
          outF[idx] = res[idx] + v;
        } else if (EPI == 2) {
          const size_t idx = (size_t)row * N + col;
          float g = bf2f(gate[idx]);
          outB[idx] = f2bf(v * g / (1.f + __expf(-g)));
        } else {
          unsigned short* dst = (col < 2048) ? qb_ : (col < 4096) ? kb_ : vb_;
          dst[(size_t)row * 2048 + (col & 2047)] = f2bf(v);
        }
      }
}

// ---------------- causal flash attention v3: swapped QK^T, in-register softmax ----------------
__global__ __launch_bounds__(256) void attn_kernel(const unsigned short* __restrict__ Q,
                                                   const unsigned short* __restrict__ Kb,
                                                   const unsigned short* __restrict__ Vt,
                                                   unsigned short* __restrict__ Ob) {
  __shared__ unsigned short Ks[2][64 * 128];   // [kv][d], 256B rows, (row&15)<<4 swizzle
  __shared__ unsigned short Vs[2][128 * 64];   // [d][kv], 128B rows, (row&7)<<4 swizzle
  __shared__ float alS[4][32];                 // per-warp q-indexed gather scratch
  const int tid = threadIdx.x, w = tid >> 6, l = tid & 63;
  const int lq = l & 31, hi = l >> 5;
  // work mapping: XCD c = bid&7 gets heads 2c, 2c+1; k<32 heavy (j=31..16), k>=32 light (j=0..15)
  const int bid = blockIdx.x;
  const int c = bid & 7, k = bid >> 3;
  const int kk = (k < 32) ? k : (k - 32);
  const int h = 2 * c + (kk >> 4);
  const int j = (k < 32) ? (31 - (kk & 15)) : (kk & 15);
  const int qb0 = j * 128;
  const int qw0 = qb0 + w * 32;

  bf16x8 qf[8];
#pragma unroll
  for (int cq = 0; cq < 8; ++cq)
    qf[cq] = *(const bf16x8*)(Q + (size_t)(qw0 + lq) * HIDN + h * HDIM + cq * 16 + hi * 8);

  float m2 = -1e30f, lsum = 0.f;
  f32x16 o[4];
#pragma unroll
  for (int dc = 0; dc < 4; ++dc) o[dc] = (f32x16){};

  const int krow = tid >> 4, kc2 = (tid & 15) * 16;
  const int vrow = tid >> 3, vc2 = (tid & 7) * 16;
  const int nt = qb0 / 64 + 2;

#define STAGE(T, B)                                                                          \
  {                                                                                          \
    const int kv0_ = (T) * 64;                                                               \
    _Pragma("unroll")                                                                        \
    for (int i = 0; i < 4; ++i) {                                                            \
      const int row = i * 16 + krow;                                                         \
      gl_lds16(Kb + (size_t)(kv0_ + row) * HIDN + h * HDIM + ((kc2 ^ ((row & 15) << 4)) >> 1), \
               &Ks[B][i * 2048 + tid * 8]);                                                  \
    }                                                                                        \
    _Pragma("unroll")                                                                        \
    for (int i = 0; i < 4; ++i) {                                                            \
      const int row = i * 32 + vrow;                                                         \
      gl_lds16(Vt + (size_t)(h * HDIM + row) * SEQ + kv0_ + ((vc2 ^ ((row & 7) << 4)) >> 1),   \
               &Vs[B][i * 2048 + tid * 8]);                                                  \
    }                                                                                        \
  }
#define LDK(row_, c_) (*(const bf16x8*)&Ks[cur][(row_) * 128 + ((((c_) * 32 + hi * 16) ^ (((row_) & 15) << 4)) >> 1)])
#define LDV(row_, ks_) (*(const bf16x8*)&Vs[cur][(row_) * 64 + ((((ks_) * 32 + hi * 16) ^ (((row_) & 7) << 4)) >> 1)])

  STAGE(0, 0);
  __syncthreads();

  for (int t = 0; t < nt; ++t) {
    const int cur = t & 1, kv0 = t * 64;
    if (t + 1 < nt) STAGE(t + 1, cur ^ 1);

    if (kv0 <= qw0 + 31) {
      f32x16 s0 = {}, s1 = {};
      __builtin_amdgcn_s_setprio(1);
#pragma unroll
      for (int cq = 0; cq < 8; ++cq) {
        s0 = __builtin_amdgcn_mfma_f32_32x32x16_bf16(LDK(lq, cq), qf[cq], s0, 0, 0, 0);
        s1 = __builtin_amdgcn_mfma_f32_32x32x16_bf16(LDK(32 + lq, cq), qf[cq], s1, 0, 0, 0);
      }
      __builtin_amdgcn_s_setprio(0);
      const float SC2 = 0.08838834764831845f * 1.44269504088896f;
#pragma unroll
      for (int r = 0; r < 16; ++r) { s0[r] *= SC2; s1[r] *= SC2; }
      if (kv0 + 63 > qw0) {
        const int qi = qw0 + lq;
#pragma unroll
        for (int r = 0; r < 16; ++r) {
          const int kvr = kv0 + (r & 3) + 8 * (r >> 2) + 4 * hi;
          if (kvr > qi) s0[r] = -1e30f;
          if (kvr + 32 > qi) s1[r] = -1e30f;
        }
      }
      float vm = s0[0];
#pragma unroll
      for (int r = 1; r < 16; ++r) vm = fmaxf(vm, s0[r]);
#pragma unroll
      for (int r = 0; r < 16; ++r) vm = fmaxf(vm, s1[r]);
      vm = fmaxf(vm, __shfl_xor(vm, 32, 64));
      float al = 1.f;
      if (!__all(vm <= m2 + 11.54f)) {
        const float mn = fmaxf(m2, vm);
        al = exp2f(m2 - mn);
        m2 = mn;
        if (l < 32) alS[w][l] = al;
#pragma unroll
        for (int r = 0; r < 16; ++r) {
          const float a = alS[w][(r & 3) + 8 * (r >> 2) + 4 * hi];
          o[0][r] *= a; o[1][r] *= a; o[2][r] *= a; o[3][r] *= a;
        }
      }
      float p[32];
#pragma unroll
      for (int r = 0; r < 16; ++r) { p[r] = exp2f(s0[r] - m2); p[16 + r] = exp2f(s1[r] - m2); }
      float rsum = 0.f;
#pragma unroll
      for (int r = 0; r < 32; ++r) rsum += p[r];
      lsum = lsum * al + (rsum + __shfl_xor(rsum, 32, 64));
      bf16x8 pa[4];
#pragma unroll
      for (int hh = 0; hh < 2; ++hh) {
        unsigned ua[8];
#pragma unroll
        for (int i = 0; i < 8; ++i) ua[i] = cvtpk(p[hh * 16 + 2 * i], p[hh * 16 + 2 * i + 1]);
        plswap(ua[0], ua[2]); plswap(ua[1], ua[3]);
        plswap(ua[4], ua[6]); plswap(ua[5], ua[7]);
        pa[hh * 2]     = mk_pa(ua[0], ua[1], ua[2], ua[3]);
        pa[hh * 2 + 1] = mk_pa(ua[4], ua[5], ua[6], ua[7]);
      }
      __builtin_amdgcn_s_setprio(1);
#pragma unroll
      for (int dc = 0; dc < 4; ++dc) {
        const int vr = dc * 32 + lq;
#pragma unroll
        for (int ks = 0; ks < 4; ++ks)
          o[dc] = __builtin_amdgcn_mfma_f32_32x32x16_bf16(pa[ks], LDV(vr, ks), o[dc], 0, 0, 0);
      }
      __builtin_amdgcn_s_setprio(0);
    }
    __syncthreads();
  }
#undef STAGE
#undef LDK
#undef LDV

  if (l < 32) alS[w][l] = 1.f / lsum;
#pragma unroll
  for (int r = 0; r < 16; ++r) {
    const int q = (r & 3) + 8 * (r >> 2) + 4 * hi;
    const float rr = alS[w][q];
    const size_t rowb = (size_t)(qw0 + q) * HIDN + h * HDIM + lq;
    Ob[rowb]      = f2bf(o[0][r] * rr);
    Ob[rowb + 32] = f2bf(o[1][r] * rr);
    Ob[rowb + 64] = f2bf(o[2][r] * rr);
    Ob[rowb + 96] = f2bf(o[3][r] * rr);
  }
}

extern "C" void kernel_launch(void* const* d_in, const int* in_sizes, int n_in,
                              void* d_out, int out_size, void* d_ws, size_t ws_size,
                              hipStream_t stream) {
  const float* x    = (const float*)d_in[0];
  const float* fcos = (const float*)d_in[1];
  const float* fsin = (const float*)d_in[2];
  // d_in[3] = mask: causal computed directly
  const float* wq = (const float*)d_in[4];
  const float* wk = (const float*)d_in[5];
  const float* wv = (const float*)d_in[6];
  const float* wo = (const float*)d_in[7];
  const float* wg = (const float*)d_in[8];
  const float* wu = (const float*)d_in[9];
  const float* wd = (const float*)d_in[10];
  const float* n1 = (const float*)d_in[11];
  const float* n2 = (const float*)d_in[12];
  float* out = (float*)d_out;

  const size_t HH = (size_t)HIDN * HIDN, HI = (size_t)HIDN * INTERN;
  const size_t SH = (size_t)SEQ * HIDN, SI = (size_t)SEQ * INTERN;
  unsigned short* p = (unsigned short*)d_ws;
  unsigned short* wqT = p; p += HH;   // wqT|wkT|wvT contiguous => fused QKV B-matrix [6144][2048]
  unsigned short* wkT = p; p += HH;
  unsigned short* wvT = p; p += HH;
  unsigned short* woT = p; p += HH;
  unsigned short* wgT = p; p += HI;
  unsigned short* wuT = p; p += HI;
  unsigned short* wdT = p; p += HI;
  unsigned short* xn  = p; p += SH;   // xn, later hn
  unsigned short* qb  = p; p += SH;
  unsigned short* kb  = p; p += SH;
  unsigned short* vb  = p; p += SH;   // v, later attention out
  unsigned short* vt  = p; p += SH;
  unsigned short* ffnb = p; p += SI;
  float* hbuf = (float*)p;            // SH floats
  unsigned short* gbuf = qb;          // gate reuses dead q/k/(part of v) region

  rmsnorm_kernel<<<SEQ, 256, 0, stream>>>(x, n1, xn);
  dim3 tHH(HIDN / 32, HIDN / 32);
  transpose_f2b<<<tHH, 256, 0, stream>>>(wq, wqT, HIDN, HIDN);
  transpose_f2b<<<tHH, 256, 0, stream>>>(wk, wkT, HIDN, HIDN);
  transpose_f2b<<<tHH, 256, 0, stream>>>(wv, wvT, HIDN, HIDN);
  transpose_f2b<<<tHH, 256, 0, stream>>>(wo, woT, HIDN, HIDN);
  transpose_f2b<<<dim3(INTERN / 32, HIDN / 32), 256, 0, stream>>>(wg, wgT, HIDN, INTERN);
  transpose_f2b<<<dim3(INTERN / 32, HIDN / 32), 256, 0, stream>>>(wu, wuT, HIDN, INTERN);
  transpose_f2b<<<dim3(HIDN / 32, INTERN / 32), 256, 0, stream>>>(wd, wdT, INTERN, HIDN);

  // fused QKV: C[4096][6144], split-stored into qb/kb/vb
  gemm2<3><<<768, 512, 0, stream>>>(xn, wqT, SEQ, 3 * HIDN, HIDN, 24,
                                    nullptr, nullptr, nullptr, nullptr, qb, kb, vb);
  rope_kernel<<<SEQ, 256, 0, stream>>>(qb, fcos, fsin);
  rope_kernel<<<SEQ, 256, 0, stream>>>(kb, fcos, fsin);
  transpose_b2b<<<dim3(HIDN / 32, SEQ / 32), 256, 0, stream>>>(vb, vt, SEQ, HIDN);
  attn_kernel<<<dim3(SEQ / 128 * NHEAD), 256, 0, stream>>>(qb, kb, vt, vb);
  gemm2<1><<<256, 512, 0, stream>>>(vb, woT, SEQ, HIDN, HIDN, 8,
                                    hbuf, nullptr, x, nullptr, nullptr, nullptr, nullptr);
  rmsnorm_kernel<<<SEQ, 256, 0, stream>>>(hbuf, n2, xn);
  gemm2<0><<<704, 512, 0, stream>>>(xn, wgT, SEQ, INTERN, HIDN, 22,
                                    nullptr, gbuf, nullptr, nullptr, nullptr, nullptr, nullptr);
  gemm2<2><<<704, 512, 0, stream>>>(xn, wuT, SEQ, INTERN, HIDN, 22,
                                    nullptr, ffnb, nullptr, gbuf, nullptr, nullptr, nullptr);
  gemm2<1><<<256, 512, 0, stream>>>(ffnb, wdT, SEQ, HIDN, INTERN, 8,
                                    out, nullptr, hbuf, nullptr, nullptr, nullptr, nullptr);
}